// Round 1
// baseline (2121.106 us; speedup 1.0000x reference)
//
#include <hip/hip_runtime.h>

#define NN 100000
#define NE 1600000
#define KF 128
#define NCLS 40
#define EPSV 1e-5f

static __device__ __forceinline__ int imax1(int x) { return x > 0 ? x : 1; }

// ---------------- graph build ----------------
__global__ void k_deg(const int* __restrict__ src, const int* __restrict__ dst,
                      int* __restrict__ deg_out, int* __restrict__ deg_in) {
  int e = blockIdx.x * blockDim.x + threadIdx.x;
  if (e < NE) {
    atomicAdd(&deg_out[src[e]], 1);
    atomicAdd(&deg_in[dst[e]], 1);
  }
}

__global__ void k_scan(const int* __restrict__ deg, int* __restrict__ ptr) {
  __shared__ int sm[1024];
  int t = threadIdx.x;
  const int per = (NN + 1023) / 1024;
  int start = t * per;
  int s = 0;
  for (int i = 0; i < per; ++i) {
    int idx = start + i;
    if (idx < NN) s += deg[idx];
  }
  sm[t] = s;
  __syncthreads();
  for (int d = 1; d < 1024; d <<= 1) {
    int v = (t >= d) ? sm[t - d] : 0;
    __syncthreads();
    sm[t] += v;
    __syncthreads();
  }
  int off = sm[t] - s;  // exclusive prefix
  for (int i = 0; i < per; ++i) {
    int idx = start + i;
    if (idx < NN) { ptr[idx] = off; off += deg[idx]; }
  }
  if (t == 1023) ptr[NN] = sm[1023];
}

__global__ void k_rsq(const int* __restrict__ deg_out, const int* __restrict__ deg_in,
                      float* __restrict__ ro, float* __restrict__ ri) {
  int i = blockIdx.x * blockDim.x + threadIdx.x;
  if (i < NN) {
    ro[i] = rsqrtf((float)imax1(deg_out[i]));
    ri[i] = rsqrtf((float)imax1(deg_in[i]));
  }
}

__global__ void k_scatter(const int* __restrict__ src, const int* __restrict__ dst,
                          const int* __restrict__ ptr_f, const int* __restrict__ ptr_r,
                          int* __restrict__ fill_f, int* __restrict__ fill_r,
                          int* __restrict__ idx_f, int* __restrict__ idx_r) {
  int e = blockIdx.x * blockDim.x + threadIdx.x;
  if (e < NE) {
    int s = src[e], d = dst[e];
    idx_f[ptr_f[d] + atomicAdd(&fill_f[d], 1)] = s;
    idx_r[ptr_r[s] + atomicAdd(&fill_r[s], 1)] = d;
  }
}

// ---------------- SpMM: out[v] = wout[v] * sum_{u in row v} in[u]*wg[u] ----------------
__global__ __launch_bounds__(256) void k_spmm(const float* __restrict__ in,
                      const int* __restrict__ ptr, const int* __restrict__ idx,
                      const float* __restrict__ wg, const float* __restrict__ wout,
                      float* __restrict__ out) {
  int wid = (blockIdx.x * blockDim.x + threadIdx.x) >> 6;  // one wave per row
  int lane = threadIdx.x & 63;
  if (wid >= NN) return;
  int beg = ptr[wid], end = ptr[wid + 1];
  float ax = 0.f, ay = 0.f;
  for (int p = beg; p < end; ++p) {
    int u = idx[p];
    float w = wg[u];
    float2 v = ((const float2*)(in + (size_t)u * KF))[lane];
    ax += w * v.x;
    ay += w * v.y;
  }
  float w = wout[wid];
  ((float2*)(out + (size_t)wid * KF))[lane] = make_float2(ax * w, ay * w);
}

// ---------------- matmul + elementwise max: out = max(hprev, A@W (+bias)) ----------------
// block: 256 thr, tile 64 rows x 128 cols; thread: 4 rows x 8 cols
template <bool HAS_BIAS>
__global__ __launch_bounds__(256) void k_mm_max(const float* __restrict__ A, const float* __restrict__ W,
                        const float* __restrict__ bias,
                        const float* __restrict__ hprev, float* __restrict__ out) {
  __shared__ float Al[32][68];    // [k][row], padded: row base 272B (16B-aligned)
  __shared__ float Wl[32][128];   // [k][col]
  int tid = threadIdx.x;
  int tx = tid & 15;   // col group (8 cols)
  int ty = tid >> 4;   // row group (4 rows)
  int r0 = blockIdx.x * 64;
  float acc[4][8];
#pragma unroll
  for (int i = 0; i < 4; ++i)
#pragma unroll
    for (int j = 0; j < 8; ++j) acc[i][j] = 0.f;

  for (int kc = 0; kc < KF; kc += 32) {
#pragma unroll
    for (int it = 0; it < 2; ++it) {  // A chunk 64x32 -> transposed LDS
      int j = tid + it * 256;
      int row = j >> 3;
      int c4 = j & 7;
      float4 v = make_float4(0.f, 0.f, 0.f, 0.f);
      int gr = r0 + row;
      if (gr < NN) v = *(const float4*)(A + (size_t)gr * KF + kc + c4 * 4);
      Al[c4 * 4 + 0][row] = v.x;
      Al[c4 * 4 + 1][row] = v.y;
      Al[c4 * 4 + 2][row] = v.z;
      Al[c4 * 4 + 3][row] = v.w;
    }
#pragma unroll
    for (int it = 0; it < 4; ++it) {  // W chunk 32x128
      int j = tid + it * 256;
      int row = j >> 5;
      int c4 = j & 31;
      *(float4*)&Wl[row][c4 * 4] = *(const float4*)(W + (size_t)(kc + row) * KF + c4 * 4);
    }
    __syncthreads();
#pragma unroll
    for (int k = 0; k < 32; ++k) {
      float4 a = *(const float4*)&Al[k][ty * 4];
      float4 w0 = *(const float4*)&Wl[k][tx * 8];
      float4 w1 = *(const float4*)&Wl[k][tx * 8 + 4];
      float av[4] = {a.x, a.y, a.z, a.w};
      float wv[8] = {w0.x, w0.y, w0.z, w0.w, w1.x, w1.y, w1.z, w1.w};
#pragma unroll
      for (int i = 0; i < 4; ++i)
#pragma unroll
        for (int jj = 0; jj < 8; ++jj) acc[i][jj] += av[i] * wv[jj];
    }
    __syncthreads();
  }
#pragma unroll
  for (int i = 0; i < 4; ++i) {
    int gr = r0 + ty * 4 + i;
    if (gr >= NN) continue;
#pragma unroll
    for (int jj = 0; jj < 8; ++jj) {
      int c = tx * 8 + jj;
      float v = acc[i][jj];
      if (HAS_BIAS) v += bias[c];
      float hp = hprev[(size_t)gr * KF + c];
      out[(size_t)gr * KF + c] = fmaxf(hp, v);
    }
  }
}

// ---------------- dual matmul: out = A1@W1 + A2@W2 ----------------
__global__ __launch_bounds__(256) void k_mm_dual(const float* __restrict__ A1, const float* __restrict__ W1,
                         const float* __restrict__ A2, const float* __restrict__ W2,
                         float* __restrict__ out) {
  __shared__ float Al1[32][68];
  __shared__ float Al2[32][68];
  __shared__ float Wl1[32][128];
  __shared__ float Wl2[32][128];
  int tid = threadIdx.x;
  int tx = tid & 15;
  int ty = tid >> 4;
  int r0 = blockIdx.x * 64;
  float acc[4][8];
#pragma unroll
  for (int i = 0; i < 4; ++i)
#pragma unroll
    for (int j = 0; j < 8; ++j) acc[i][j] = 0.f;

  for (int kc = 0; kc < KF; kc += 32) {
#pragma unroll
    for (int it = 0; it < 2; ++it) {
      int j = tid + it * 256;
      int row = j >> 3;
      int c4 = j & 7;
      int gr = r0 + row;
      float4 v1 = make_float4(0.f, 0.f, 0.f, 0.f);
      float4 v2 = make_float4(0.f, 0.f, 0.f, 0.f);
      if (gr < NN) {
        v1 = *(const float4*)(A1 + (size_t)gr * KF + kc + c4 * 4);
        v2 = *(const float4*)(A2 + (size_t)gr * KF + kc + c4 * 4);
      }
      Al1[c4 * 4 + 0][row] = v1.x; Al1[c4 * 4 + 1][row] = v1.y;
      Al1[c4 * 4 + 2][row] = v1.z; Al1[c4 * 4 + 3][row] = v1.w;
      Al2[c4 * 4 + 0][row] = v2.x; Al2[c4 * 4 + 1][row] = v2.y;
      Al2[c4 * 4 + 2][row] = v2.z; Al2[c4 * 4 + 3][row] = v2.w;
    }
#pragma unroll
    for (int it = 0; it < 4; ++it) {
      int j = tid + it * 256;
      int row = j >> 5;
      int c4 = j & 31;
      *(float4*)&Wl1[row][c4 * 4] = *(const float4*)(W1 + (size_t)(kc + row) * KF + c4 * 4);
      *(float4*)&Wl2[row][c4 * 4] = *(const float4*)(W2 + (size_t)(kc + row) * KF + c4 * 4);
    }
    __syncthreads();
#pragma unroll
    for (int k = 0; k < 32; ++k) {
      float4 a1 = *(const float4*)&Al1[k][ty * 4];
      float4 w10 = *(const float4*)&Wl1[k][tx * 8];
      float4 w11 = *(const float4*)&Wl1[k][tx * 8 + 4];
      float av1[4] = {a1.x, a1.y, a1.z, a1.w};
      float wv1[8] = {w10.x, w10.y, w10.z, w10.w, w11.x, w11.y, w11.z, w11.w};
#pragma unroll
      for (int i = 0; i < 4; ++i)
#pragma unroll
        for (int jj = 0; jj < 8; ++jj) acc[i][jj] += av1[i] * wv1[jj];
      float4 a2 = *(const float4*)&Al2[k][ty * 4];
      float4 w20 = *(const float4*)&Wl2[k][tx * 8];
      float4 w21 = *(const float4*)&Wl2[k][tx * 8 + 4];
      float av2[4] = {a2.x, a2.y, a2.z, a2.w};
      float wv2[8] = {w20.x, w20.y, w20.z, w20.w, w21.x, w21.y, w21.z, w21.w};
#pragma unroll
      for (int i = 0; i < 4; ++i)
#pragma unroll
        for (int jj = 0; jj < 8; ++jj) acc[i][jj] += av2[i] * wv2[jj];
    }
    __syncthreads();
  }
#pragma unroll
  for (int i = 0; i < 4; ++i) {
    int gr = r0 + ty * 4 + i;
    if (gr >= NN) continue;
#pragma unroll
    for (int jj = 0; jj < 8; ++jj) {
      out[(size_t)gr * KF + tx * 8 + jj] = acc[i][jj];
    }
  }
}

// ---------------- column stats (mean/var over rows) ----------------
__global__ __launch_bounds__(256) void k_stats_part(const float* __restrict__ C, float* __restrict__ part) {
  int b = blockIdx.x;
  int col = threadIdx.x & 127;
  int half = threadIdx.x >> 7;
  const int chunk = (NN + 511) / 512;
  int rbeg = b * chunk;
  int rend = rbeg + chunk;
  if (rend > NN) rend = NN;
  float s = 0.f, q = 0.f;
  for (int r = rbeg + half; r < rend; r += 2) {
    float v = C[(size_t)r * KF + col];
    s += v;
    q += v * v;
  }
  __shared__ float sm[256], qm[256];
  sm[threadIdx.x] = s;
  qm[threadIdx.x] = q;
  __syncthreads();
  if (half == 0) {
    part[b * 256 + col] = sm[col] + sm[col + 128];
    part[b * 256 + 128 + col] = qm[col] + qm[col + 128];
  }
}

__global__ void k_stats_fin(const float* __restrict__ part, const float* __restrict__ gamma,
                            const float* __restrict__ beta, float* __restrict__ ab) {
  int c = threadIdx.x;  // 128 threads
  float s = 0.f, q = 0.f;
  for (int b = 0; b < 512; ++b) {
    s += part[b * 256 + c];
    q += part[b * 256 + 128 + c];
  }
  float mu = s / (float)NN;
  float var = q / (float)NN - mu * mu;
  float rs = rsqrtf(var + EPSV);
  float a = gamma[c] * rs;
  ab[c] = a;
  ab[128 + c] = beta[c] - mu * a;
}

__global__ __launch_bounds__(256) void k_norm(float* __restrict__ h, const float* __restrict__ ab) {
  int i = blockIdx.x * blockDim.x + threadIdx.x;  // over NN*KF/4 float4s
  if (i >= NN * KF / 4) return;
  float4 v = ((float4*)h)[i];
  int c = (i & 31) * 4;
  float4 r;
  r.x = fmaxf(0.f, v.x * ab[c + 0] + ab[128 + c + 0]);
  r.y = fmaxf(0.f, v.y * ab[c + 1] + ab[128 + c + 1]);
  r.z = fmaxf(0.f, v.z * ab[c + 2] + ab[128 + c + 2]);
  r.w = fmaxf(0.f, v.w * ab[c + 3] + ab[128 + c + 3]);
  ((float4*)h)[i] = r;
}

// ---------------- final layer: out[r][j] = sum_k A1[r][k]W1[k][j] + A2[r][k]W2[k][j] + bias[j] ----------------
__global__ __launch_bounds__(256) void k_final(const float* __restrict__ A1, const float* __restrict__ W1,
                       const float* __restrict__ A2, const float* __restrict__ W2,
                       const float* __restrict__ bias, float* __restrict__ out) {
  __shared__ float W1l[KF][NCLS + 1];
  __shared__ float W2l[KF][NCLS + 1];
  for (int j = threadIdx.x; j < KF * NCLS; j += 256) {
    W1l[j / NCLS][j % NCLS] = W1[j];
    W2l[j / NCLS][j % NCLS] = W2[j];
  }
  __syncthreads();
  int r = blockIdx.x * blockDim.x + threadIdx.x;
  if (r >= NN) return;
  float acc[NCLS];
#pragma unroll
  for (int j = 0; j < NCLS; ++j) acc[j] = bias[j];
  for (int k = 0; k < KF; k += 4) {
    float4 a1 = *(const float4*)(A1 + (size_t)r * KF + k);
    float4 a2 = *(const float4*)(A2 + (size_t)r * KF + k);
    float x1[4] = {a1.x, a1.y, a1.z, a1.w};
    float x2[4] = {a2.x, a2.y, a2.z, a2.w};
#pragma unroll
    for (int m = 0; m < 4; ++m) {
#pragma unroll
      for (int j = 0; j < NCLS; ++j)
        acc[j] += x1[m] * W1l[k + m][j] + x2[m] * W2l[k + m][j];
    }
  }
  for (int j = 0; j < NCLS; ++j) out[(size_t)r * NCLS + j] = acc[j];
}

extern "C" void kernel_launch(void* const* d_in, const int* in_sizes, int n_in,
                              void* d_out, int out_size, void* d_ws, size_t ws_size,
                              hipStream_t stream) {
  const float* feat  = (const float*)d_in[0];
  const float* Wb    = (const float*)d_in[1];   // 3x128x128
  const float* bb2   = (const float*)d_in[2];   // 128
  const float* Wh01  = (const float*)d_in[3];   // 2x128x128
  const float* W2    = (const float*)d_in[4];   // 128x40
  const float* b2    = (const float*)d_in[5];   // 40
  const float* Wl01  = (const float*)d_in[6];   // 2x128x128
  const float* Wl2   = (const float*)d_in[7];   // 128x40
  const float* gamma = (const float*)d_in[8];   // 2x128
  const float* beta  = (const float*)d_in[9];   // 2x128
  const int* src = (const int*)d_in[10];
  const int* dst = (const int*)d_in[11];
  float* out = (float*)d_out;

  char* ws = (char*)d_ws;
  size_t off = 0;
  auto alloc = [&](size_t b) { size_t o = off; off += (b + 255) & ~(size_t)255; return o; };
  size_t z0 = alloc((size_t)4 * NN * 4);  // deg_out|deg_in|fill_f|fill_r contiguous (one memset)
  int* deg_out = (int*)(ws + z0);
  int* deg_in = deg_out + NN;
  int* fill_f = deg_in + NN;
  int* fill_r = fill_f + NN;
  int* ptr_f = (int*)(ws + alloc((size_t)(NN + 1) * 4));
  int* ptr_r = (int*)(ws + alloc((size_t)(NN + 1) * 4));
  int* idx_f = (int*)(ws + alloc((size_t)NE * 4));
  int* idx_r = (int*)(ws + alloc((size_t)NE * 4));
  float* ro = (float*)(ws + alloc((size_t)NN * 4));
  float* ri = (float*)(ws + alloc((size_t)NN * 4));
  float* aggb = (float*)(ws + alloc((size_t)NN * KF * 4));
  float* hmax = (float*)(ws + alloc((size_t)NN * KF * 4));
  float* hbuf = (float*)(ws + alloc((size_t)NN * KF * 4));
  float* t1 = (float*)(ws + alloc((size_t)NN * KF * 4));
  float* part = (float*)(ws + alloc((size_t)512 * 256 * 4));
  float* ab = (float*)(ws + alloc((size_t)256 * 4));
  (void)ws_size;

  hipMemsetAsync(ws + z0, 0, (size_t)4 * NN * 4, stream);
  int eb = (NE + 255) / 256;
  k_deg<<<eb, 256, 0, stream>>>(src, dst, deg_out, deg_in);
  k_scan<<<1, 1024, 0, stream>>>(deg_in, ptr_f);
  k_scan<<<1, 1024, 0, stream>>>(deg_out, ptr_r);
  k_rsq<<<(NN + 255) / 256, 256, 0, stream>>>(deg_out, deg_in, ro, ri);
  k_scatter<<<eb, 256, 0, stream>>>(src, dst, ptr_f, ptr_r, fill_f, fill_r, idx_f, idx_r);

  int sb = (NN * 64 + 255) / 256;  // one wave per row
  // reverse conv SpMM once: aggb[u] = ro[u] * sum_{dst of u's out-edges} feat[d]*ri[d]
  k_spmm<<<sb, 256, 0, stream>>>(feat, ptr_r, idx_r, ri, ro, aggb);

  const float* hcur = feat;
  int mb = (NN + 63) / 64;
  for (int layer = 0; layer < 3; ++layer) {
    const float* Wbl = Wb + (size_t)layer * KF * KF;
    if (layer == 2)
      k_mm_max<true><<<mb, 256, 0, stream>>>(aggb, Wbl, bb2, hcur, hmax);
    else
      k_mm_max<false><<<mb, 256, 0, stream>>>(aggb, Wbl, nullptr, hcur, hmax);
    k_spmm<<<sb, 256, 0, stream>>>(hmax, ptr_f, idx_f, ro, ri, t1);
    if (layer < 2) {
      k_mm_dual<<<mb, 256, 0, stream>>>(t1, Wh01 + (size_t)layer * KF * KF, hmax,
                                        Wl01 + (size_t)layer * KF * KF, hbuf);
      k_stats_part<<<512, 256, 0, stream>>>(hbuf, part);
      k_stats_fin<<<1, 128, 0, stream>>>(part, gamma + layer * KF, beta + layer * KF, ab);
      k_norm<<<(NN * KF / 4 + 255) / 256, 256, 0, stream>>>(hbuf, ab);
      hcur = hbuf;
    } else {
      k_final<<<(NN + 255) / 256, 256, 0, stream>>>(t1, W2, hmax, Wl2, b2, out);
    }
  }
}

// Round 3
// 1649.955 us; speedup vs baseline: 1.2856x; 1.2856x over previous
//
#include <hip/hip_runtime.h>

#define NN 100000
#define NE 1600000
#define KF 128
#define NCLS 40
#define EPSV 1e-5f

typedef short bf16x8 __attribute__((ext_vector_type(8)));
typedef float f32x4 __attribute__((ext_vector_type(4)));
typedef unsigned short ushort;
typedef unsigned int uint;
typedef ushort ush8 __attribute__((ext_vector_type(8)));

static __device__ __forceinline__ int imax1(int x) { return x > 0 ? x : 1; }

static __device__ __forceinline__ ushort f2b(float f) {  // fp32 -> bf16 RNE
  uint u = __builtin_bit_cast(uint, f);
  u += 0x7fffu + ((u >> 16) & 1u);
  return (ushort)(u >> 16);
}
static __device__ __forceinline__ float b2f(uint bits16) {
  return __builtin_bit_cast(float, bits16 << 16);
}

// ---------------- graph build ----------------
__global__ void k_deg(const int* __restrict__ src, const int* __restrict__ dst,
                      int* __restrict__ deg_out, int* __restrict__ deg_in) {
  int e = blockIdx.x * blockDim.x + threadIdx.x;
  if (e < NE) {
    atomicAdd(&deg_out[src[e]], 1);
    atomicAdd(&deg_in[dst[e]], 1);
  }
}

__global__ void k_scan(const int* __restrict__ deg, int* __restrict__ ptr) {
  __shared__ int sm[1024];
  int t = threadIdx.x;
  const int per = (NN + 1023) / 1024;
  int start = t * per;
  int s = 0;
  for (int i = 0; i < per; ++i) {
    int idx = start + i;
    if (idx < NN) s += deg[idx];
  }
  sm[t] = s;
  __syncthreads();
  for (int d = 1; d < 1024; d <<= 1) {
    int v = (t >= d) ? sm[t - d] : 0;
    __syncthreads();
    sm[t] += v;
    __syncthreads();
  }
  int off = sm[t] - s;  // exclusive prefix
  for (int i = 0; i < per; ++i) {
    int idx = start + i;
    if (idx < NN) { ptr[idx] = off; off += deg[idx]; }
  }
  if (t == 1023) ptr[NN] = sm[1023];
}

__global__ void k_rsq(const int* __restrict__ deg_out, const int* __restrict__ deg_in,
                      float* __restrict__ ro, float* __restrict__ ri) {
  int i = blockIdx.x * blockDim.x + threadIdx.x;
  if (i < NN) {
    ro[i] = rsqrtf((float)imax1(deg_out[i]));
    ri[i] = rsqrtf((float)imax1(deg_in[i]));
  }
}

__global__ void k_scatter(const int* __restrict__ src, const int* __restrict__ dst,
                          const int* __restrict__ ptr_f, const int* __restrict__ ptr_r,
                          int* __restrict__ fill_f, int* __restrict__ fill_r,
                          int* __restrict__ idx_f, int* __restrict__ idx_r) {
  int e = blockIdx.x * blockDim.x + threadIdx.x;
  if (e < NE) {
    int s = src[e], d = dst[e];
    idx_f[ptr_f[d] + atomicAdd(&fill_f[d], 1)] = s;
    idx_r[ptr_r[s] + atomicAdd(&fill_r[s], 1)] = d;
  }
}

// ---------------- fp32 -> bf16 bulk convert (feat) ----------------
__global__ __launch_bounds__(256) void k_convF(const float* __restrict__ in, ushort* __restrict__ out) {
  int i = (blockIdx.x * blockDim.x + threadIdx.x) * 8;  // grid sized exactly
  float4 a = *(const float4*)(in + i);
  float4 b = *(const float4*)(in + i + 4);
  ush8 o;
  o[0] = f2b(a.x); o[1] = f2b(a.y); o[2] = f2b(a.z); o[3] = f2b(a.w);
  o[4] = f2b(b.x); o[5] = f2b(b.y); o[6] = f2b(b.z); o[7] = f2b(b.w);
  *(ush8*)(out + i) = o;
}

// ---------------- weight convert+transpose: wt[n][k] = bf16(W[k][n]) ----------------
// layout: [0..3)x16384 Wb | [3..5)x16384 Wh01 | [5..7)x16384 Wl01 | 40x128 W2 | 40x128 Wl2
#define WT_W2 (7 * 16384)
#define WT_L2 (WT_W2 + NCLS * KF)
__global__ __launch_bounds__(256) void k_convW(const float* __restrict__ Wb, const float* __restrict__ Wh01,
                       const float* __restrict__ Wl01, const float* __restrict__ W2,
                       const float* __restrict__ Wl2, ushort* __restrict__ wt) {
  int i = blockIdx.x * blockDim.x + threadIdx.x;  // grid sized exactly (124928)
  float v;
  if (i < WT_W2) {
    int m = i >> 14, r = (i >> 7) & 127, k = i & 127;
    const float* srcm = (m < 3) ? (Wb + m * 16384)
                      : (m < 5) ? (Wh01 + (m - 3) * 16384)
                                : (Wl01 + (m - 5) * 16384);
    v = srcm[k * KF + r];
  } else {
    int j = i - WT_W2;
    int m2 = j / (NCLS * KF);
    int t = j - m2 * (NCLS * KF);
    int n = t >> 7, k = t & 127;
    v = (m2 ? Wl2 : W2)[k * NCLS + n];
  }
  wt[i] = f2b(v);
}

// ---------------- SpMM (bf16 in/out, fp32 accum): out[v] = wout[v]*sum in[u]*wg[u] ----------------
// one wave per row; lane handles 2 bf16 (uint) => 64*2 = 128 = KF  (round-2 fix:
// uint2 per lane covered 256 elems and stomped the next row)
__global__ __launch_bounds__(256) void k_spmm_b(const ushort* __restrict__ in,
                      const int* __restrict__ ptr, const int* __restrict__ idx,
                      const float* __restrict__ wg, const float* __restrict__ wout,
                      ushort* __restrict__ out) {
  int wid = (blockIdx.x * blockDim.x + threadIdx.x) >> 6;
  int lane = threadIdx.x & 63;
  if (wid >= NN) return;
  int beg = ptr[wid], end = ptr[wid + 1];
  float s0 = 0.f, s1 = 0.f;
  int p = beg;
  for (; p + 2 <= end; p += 2) {
    int u0 = idx[p], u1 = idx[p + 1];
    float w0 = wg[u0], w1 = wg[u1];
    uint v0 = *(const uint*)(in + (size_t)u0 * KF + lane * 2);
    uint v1 = *(const uint*)(in + (size_t)u1 * KF + lane * 2);
    s0 += w0 * b2f(v0 & 0xffffu) + w1 * b2f(v1 & 0xffffu);
    s1 += w0 * b2f(v0 >> 16)     + w1 * b2f(v1 >> 16);
  }
  if (p < end) {
    int u0 = idx[p];
    float w0 = wg[u0];
    uint v0 = *(const uint*)(in + (size_t)u0 * KF + lane * 2);
    s0 += w0 * b2f(v0 & 0xffffu);
    s1 += w0 * b2f(v0 >> 16);
  }
  float w = wout[wid];
  uint o = (uint)f2b(s0 * w) | ((uint)f2b(s1 * w) << 16);
  *(uint*)(out + (size_t)wid * KF + lane * 2) = o;
}

// ---------------- MFMA GEMM, no LDS: wave holds all A-frags in regs ----------------
// block = 4 waves, 64 rows; wave w -> rows blk*64 + w*16, all NCT*16 cols.
// EPI 0: outb = bf16(max(prev, acc(+bias)));  prev = NORMP ? relu(h*a+b) : h
// EPI 1: outf fp32 = acc   (dual-matmul output, pre-norm h)
// EPI 2: outf fp32 (N=NCLS) = acc + bias     (final layer)
template <int NCT, bool DUAL, int EPI, bool HASB, bool NORMP>
__global__ __launch_bounds__(256) void k_gemm(
    const ushort* __restrict__ A1, const ushort* __restrict__ Wt1,
    const ushort* __restrict__ A2, const ushort* __restrict__ Wt2,
    const float* __restrict__ bias, const float* __restrict__ hprev,
    const float* __restrict__ ab, float* __restrict__ outf, ushort* __restrict__ outb) {
  int lane = threadIdx.x & 63;
  int w = threadIdx.x >> 6;
  int r0 = blockIdx.x * 64 + w * 16;
  int arow = r0 + (lane & 15);
  if (arow > NN - 1) arow = NN - 1;
  int k0 = (lane >> 4) * 8;

  bf16x8 a1[4], a2[4];
#pragma unroll
  for (int ks = 0; ks < 4; ++ks) {
    a1[ks] = *(const bf16x8*)(A1 + (size_t)arow * KF + ks * 32 + k0);
    if (DUAL) a2[ks] = *(const bf16x8*)(A2 + (size_t)arow * KF + ks * 32 + k0);
  }
  f32x4 acc[NCT];
#pragma unroll
  for (int ct = 0; ct < NCT; ++ct) acc[ct] = (f32x4){0.f, 0.f, 0.f, 0.f};

#pragma unroll
  for (int ks = 0; ks < 4; ++ks) {
#pragma unroll
    for (int ct = 0; ct < NCT; ++ct) {
      int ncol = ct * 16 + (lane & 15);
      if (EPI == 2 && ncol > NCLS - 1) ncol = NCLS - 1;
      bf16x8 b1 = *(const bf16x8*)(Wt1 + (size_t)ncol * KF + ks * 32 + k0);
      acc[ct] = __builtin_amdgcn_mfma_f32_16x16x32_bf16(a1[ks], b1, acc[ct], 0, 0, 0);
      if (DUAL) {
        bf16x8 b2 = *(const bf16x8*)(Wt2 + (size_t)ncol * KF + ks * 32 + k0);
        acc[ct] = __builtin_amdgcn_mfma_f32_16x16x32_bf16(a2[ks], b2, acc[ct], 0, 0, 0);
      }
    }
  }

  int rbase = r0 + (lane >> 4) * 4;
#pragma unroll
  for (int ct = 0; ct < NCT; ++ct) {
    int col = ct * 16 + (lane & 15);
#pragma unroll
    for (int j = 0; j < 4; ++j) {
      int rr = rbase + j;
      if (rr >= NN) continue;
      float v = acc[ct][j];
      if (EPI == 0) {
        if (HASB) v += bias[col];
        float p = hprev[(size_t)rr * KF + col];
        if (NORMP) p = fmaxf(0.f, p * ab[col] + ab[KF + col]);
        outb[(size_t)rr * KF + col] = f2b(fmaxf(p, v));
      } else if (EPI == 1) {
        outf[(size_t)rr * KF + col] = v;
      } else {
        if (col < NCLS) outf[(size_t)rr * NCLS + col] = v + bias[col];
      }
    }
  }
}

// ---------------- column stats (mean/var over rows) on fp32 h ----------------
__global__ __launch_bounds__(256) void k_stats_part(const float* __restrict__ C, float* __restrict__ part) {
  int b = blockIdx.x;
  int col = threadIdx.x & 127;
  int half = threadIdx.x >> 7;
  const int chunk = (NN + 511) / 512;
  int rbeg = b * chunk;
  int rend = rbeg + chunk;
  if (rend > NN) rend = NN;
  float s = 0.f, q = 0.f;
  for (int r = rbeg + half; r < rend; r += 2) {
    float v = C[(size_t)r * KF + col];
    s += v;
    q += v * v;
  }
  __shared__ float sm[256], qm[256];
  sm[threadIdx.x] = s;
  qm[threadIdx.x] = q;
  __syncthreads();
  if (half == 0) {
    part[b * 256 + col] = sm[col] + sm[col + 128];
    part[b * 256 + 128 + col] = qm[col] + qm[col + 128];
  }
}

__global__ void k_stats_fin(const float* __restrict__ part, const float* __restrict__ gamma,
                            const float* __restrict__ beta, float* __restrict__ ab) {
  int c = threadIdx.x;  // 128 threads
  float s = 0.f, q = 0.f;
  for (int b = 0; b < 512; ++b) {
    s += part[b * 256 + c];
    q += part[b * 256 + 128 + c];
  }
  float mu = s / (float)NN;
  float var = q / (float)NN - mu * mu;
  float rs = rsqrtf(var + EPSV);
  float a = gamma[c] * rs;
  ab[c] = a;
  ab[KF + c] = beta[c] - mu * a;
}

extern "C" void kernel_launch(void* const* d_in, const int* in_sizes, int n_in,
                              void* d_out, int out_size, void* d_ws, size_t ws_size,
                              hipStream_t stream) {
  const float* feat  = (const float*)d_in[0];
  const float* Wb    = (const float*)d_in[1];   // 3x128x128
  const float* bb2   = (const float*)d_in[2];   // 128
  const float* Wh01  = (const float*)d_in[3];   // 2x128x128
  const float* W2    = (const float*)d_in[4];   // 128x40
  const float* b2    = (const float*)d_in[5];   // 40
  const float* Wl01  = (const float*)d_in[6];   // 2x128x128
  const float* Wl2   = (const float*)d_in[7];   // 128x40
  const float* gamma = (const float*)d_in[8];   // 2x128
  const float* beta  = (const float*)d_in[9];   // 2x128
  const int* src = (const int*)d_in[10];
  const int* dst = (const int*)d_in[11];
  float* out = (float*)d_out;

  char* ws = (char*)d_ws;
  size_t off = 0;
  auto alloc = [&](size_t b) { size_t o = off; off += (b + 255) & ~(size_t)255; return o; };
  size_t z0 = alloc((size_t)4 * NN * 4);  // deg_out|deg_in|fill_f|fill_r (one memset)
  int* deg_out = (int*)(ws + z0);
  int* deg_in = deg_out + NN;
  int* fill_f = deg_in + NN;
  int* fill_r = fill_f + NN;
  int* ptr_f = (int*)(ws + alloc((size_t)(NN + 1) * 4));
  int* ptr_r = (int*)(ws + alloc((size_t)(NN + 1) * 4));
  int* idx_f = (int*)(ws + alloc((size_t)NE * 4));
  int* idx_r = (int*)(ws + alloc((size_t)NE * 4));
  float* ro = (float*)(ws + alloc((size_t)NN * 4));
  float* ri = (float*)(ws + alloc((size_t)NN * 4));
  ushort* featb = (ushort*)(ws + alloc((size_t)NN * KF * 2));
  ushort* aggb  = (ushort*)(ws + alloc((size_t)NN * KF * 2));
  ushort* hmaxb = (ushort*)(ws + alloc((size_t)NN * KF * 2));
  ushort* t1b   = (ushort*)(ws + alloc((size_t)NN * KF * 2));
  float* hbuf = (float*)(ws + alloc((size_t)NN * KF * 4));
  float* part = (float*)(ws + alloc((size_t)512 * 256 * 4));
  float* ab = (float*)(ws + alloc((size_t)256 * 4));
  ushort* wt = (ushort*)(ws + alloc((size_t)(WT_L2 + NCLS * KF) * 2));
  (void)ws_size;

  hipMemsetAsync(ws + z0, 0, (size_t)4 * NN * 4, stream);
  int eb = (NE + 255) / 256;
  k_deg<<<eb, 256, 0, stream>>>(src, dst, deg_out, deg_in);
  k_scan<<<1, 1024, 0, stream>>>(deg_in, ptr_f);
  k_scan<<<1, 1024, 0, stream>>>(deg_out, ptr_r);
  k_rsq<<<(NN + 255) / 256, 256, 0, stream>>>(deg_out, deg_in, ro, ri);
  k_scatter<<<eb, 256, 0, stream>>>(src, dst, ptr_f, ptr_r, fill_f, fill_r, idx_f, idx_r);
  k_convW<<<(WT_L2 + NCLS * KF + 255) / 256, 256, 0, stream>>>(Wb, Wh01, Wl01, W2, Wl2, wt);
  k_convF<<<NN * KF / 8 / 256, 256, 0, stream>>>(feat, featb);

  const ushort* wtB[3] = {wt, wt + 16384, wt + 2 * 16384};
  const ushort* wtH[2] = {wt + 3 * 16384, wt + 4 * 16384};
  const ushort* wtL[2] = {wt + 5 * 16384, wt + 6 * 16384};
  const ushort* wtW2 = wt + WT_W2;
  const ushort* wtL2 = wt + WT_L2;

  int sb = (NN * 64 + 255) / 256;  // one wave per row
  // reverse conv SpMM once: aggb[u] = ro[u] * sum_{u->d reverse} featb[d]*ri[d]
  k_spmm_b<<<sb, 256, 0, stream>>>(featb, ptr_r, idx_r, ri, ro, aggb);

  int mb = (NN + 63) / 64;
  // ---- layer 0 ----
  k_gemm<8, false, 0, false, false><<<mb, 256, 0, stream>>>(
      aggb, wtB[0], nullptr, nullptr, nullptr, feat, nullptr, nullptr, hmaxb);
  k_spmm_b<<<sb, 256, 0, stream>>>(hmaxb, ptr_f, idx_f, ro, ri, t1b);
  k_gemm<8, true, 1, false, false><<<mb, 256, 0, stream>>>(
      t1b, wtH[0], hmaxb, wtL[0], nullptr, nullptr, nullptr, hbuf, nullptr);
  k_stats_part<<<512, 256, 0, stream>>>(hbuf, part);
  k_stats_fin<<<1, 128, 0, stream>>>(part, gamma, beta, ab);
  // ---- layer 1 ----  (norm of hbuf folded into hprev read via ab)
  k_gemm<8, false, 0, false, true><<<mb, 256, 0, stream>>>(
      aggb, wtB[1], nullptr, nullptr, nullptr, hbuf, ab, nullptr, hmaxb);
  k_spmm_b<<<sb, 256, 0, stream>>>(hmaxb, ptr_f, idx_f, ro, ri, t1b);
  k_gemm<8, true, 1, false, false><<<mb, 256, 0, stream>>>(
      t1b, wtH[1], hmaxb, wtL[1], nullptr, nullptr, nullptr, hbuf, nullptr);
  k_stats_part<<<512, 256, 0, stream>>>(hbuf, part);
  k_stats_fin<<<1, 128, 0, stream>>>(part, gamma + KF, beta + KF, ab);
  // ---- layer 2 ----
  k_gemm<8, false, 0, true, true><<<mb, 256, 0, stream>>>(
      aggb, wtB[2], nullptr, nullptr, bb2, hbuf, ab, nullptr, hmaxb);
  k_spmm_b<<<sb, 256, 0, stream>>>(hmaxb, ptr_f, idx_f, ro, ri, t1b);
  k_gemm<3, true, 2, false, false><<<mb, 256, 0, stream>>>(
      t1b, wtW2, hmaxb, wtL2, b2, nullptr, nullptr, out, nullptr);
}

// Round 4
// 1397.517 us; speedup vs baseline: 1.5178x; 1.1806x over previous
//
#include <hip/hip_runtime.h>

#define NN 100000
#define NE 1600000
#define KF 128
#define NCLS 40
#define EPSV 1e-5f

typedef short bf16x8 __attribute__((ext_vector_type(8)));
typedef float f32x4 __attribute__((ext_vector_type(4)));
typedef unsigned short ushort;
typedef unsigned int uint;
typedef ushort ush8 __attribute__((ext_vector_type(8)));

static __device__ __forceinline__ int imax1(int x) { return x > 0 ? x : 1; }

static __device__ __forceinline__ ushort f2b(float f) {  // fp32 -> bf16 RNE
  uint u = __builtin_bit_cast(uint, f);
  u += 0x7fffu + ((u >> 16) & 1u);
  return (ushort)(u >> 16);
}
static __device__ __forceinline__ float b2f(uint bits16) {
  return __builtin_bit_cast(float, bits16 << 16);
}

// ---------------- graph build ----------------
// degrees via atomics; atomic return value IS the edge's rank within its CSR row
__global__ void k_deg(const int* __restrict__ src, const int* __restrict__ dst,
                      int* __restrict__ deg_out, int* __restrict__ deg_in,
                      uint* __restrict__ rank) {
  int e = blockIdx.x * blockDim.x + threadIdx.x;
  if (e < NE) {
    int rs = atomicAdd(&deg_out[src[e]], 1);  // rank in reverse-CSR row src
    int rd = atomicAdd(&deg_in[dst[e]], 1);   // rank in forward-CSR row dst
    rank[e] = ((uint)rd << 16) | (uint)rs;
  }
}

__global__ void k_scan(const int* __restrict__ deg, int* __restrict__ ptr) {
  __shared__ int sm[1024];
  int t = threadIdx.x;
  const int per = (NN + 1023) / 1024;
  int start = t * per;
  int s = 0;
  for (int i = 0; i < per; ++i) {
    int idx = start + i;
    if (idx < NN) s += deg[idx];
  }
  sm[t] = s;
  __syncthreads();
  for (int d = 1; d < 1024; d <<= 1) {
    int v = (t >= d) ? sm[t - d] : 0;
    __syncthreads();
    sm[t] += v;
    __syncthreads();
  }
  int off = sm[t] - s;  // exclusive prefix
  for (int i = 0; i < per; ++i) {
    int idx = start + i;
    if (idx < NN) { ptr[idx] = off; off += deg[idx]; }
  }
  if (t == 1023) ptr[NN] = sm[1023];
}

__global__ void k_rsq(const int* __restrict__ deg_out, const int* __restrict__ deg_in,
                      float* __restrict__ ro, float* __restrict__ ri) {
  int i = blockIdx.x * blockDim.x + threadIdx.x;
  if (i < NN) {
    ro[i] = rsqrtf((float)imax1(deg_out[i]));
    ri[i] = rsqrtf((float)imax1(deg_in[i]));
  }
}

// atomic-free scatter using precomputed ranks
__global__ void k_scatter(const int* __restrict__ src, const int* __restrict__ dst,
                          const int* __restrict__ ptr_f, const int* __restrict__ ptr_r,
                          const uint* __restrict__ rank,
                          int* __restrict__ idx_f, int* __restrict__ idx_r) {
  int e = blockIdx.x * blockDim.x + threadIdx.x;
  if (e < NE) {
    int s = src[e], d = dst[e];
    uint rk = rank[e];
    idx_f[ptr_f[d] + (int)(rk >> 16)] = s;
    idx_r[ptr_r[s] + (int)(rk & 0xffffu)] = d;
  }
}

// ---------------- fp32 -> bf16 convert, row-scaled by ri (rev-SpMM pre-scale) ----------------
__global__ __launch_bounds__(256) void k_convF(const float* __restrict__ in, const float* __restrict__ ri,
                       ushort* __restrict__ out) {
  int t = blockIdx.x * blockDim.x + threadIdx.x;
  int i = t * 8;  // grid sized exactly; 16 threads per row
  float w = ri[t >> 4];
  float4 a = *(const float4*)(in + i);
  float4 b = *(const float4*)(in + i + 4);
  ush8 o;
  o[0] = f2b(a.x * w); o[1] = f2b(a.y * w); o[2] = f2b(a.z * w); o[3] = f2b(a.w * w);
  o[4] = f2b(b.x * w); o[5] = f2b(b.y * w); o[6] = f2b(b.z * w); o[7] = f2b(b.w * w);
  *(ush8*)(out + i) = o;
}

// ---------------- weight convert+transpose: wt[n][k] = bf16(W[k][n]) ----------------
// layout: [0..3)x16384 Wb | [3..5)x16384 Wh01 | [5..7)x16384 Wl01 | 40x128 W2 | 40x128 Wl2
#define WT_W2 (7 * 16384)
#define WT_L2 (WT_W2 + NCLS * KF)
__global__ __launch_bounds__(256) void k_convW(const float* __restrict__ Wb, const float* __restrict__ Wh01,
                       const float* __restrict__ Wl01, const float* __restrict__ W2,
                       const float* __restrict__ Wl2, ushort* __restrict__ wt) {
  int i = blockIdx.x * blockDim.x + threadIdx.x;  // grid sized exactly (124928)
  float v;
  if (i < WT_W2) {
    int m = i >> 14, r = (i >> 7) & 127, k = i & 127;
    const float* srcm = (m < 3) ? (Wb + m * 16384)
                      : (m < 5) ? (Wh01 + (m - 3) * 16384)
                                : (Wl01 + (m - 5) * 16384);
    v = srcm[k * KF + r];
  } else {
    int j = i - WT_W2;
    int m2 = j / (NCLS * KF);
    int t = j - m2 * (NCLS * KF);
    int n = t >> 7, k = t & 127;
    v = (m2 ? Wl2 : W2)[k * NCLS + n];
  }
  wt[i] = f2b(v);
}

// ---------------- SpMM (pre-scaled rows): out[v] = wout[v] * sum_{u in row v} in[u] ----------------
// one wave per row; lane handles 2 bf16 (uint); unroll 4 edges for MLP
__global__ __launch_bounds__(256) void k_spmm_b(const ushort* __restrict__ in,
                      const int* __restrict__ ptr, const int* __restrict__ idx,
                      const float* __restrict__ wout, ushort* __restrict__ out) {
  int wid = (blockIdx.x * blockDim.x + threadIdx.x) >> 6;
  int lane = threadIdx.x & 63;
  if (wid >= NN) return;
  int beg = ptr[wid], end = ptr[wid + 1];
  float s0 = 0.f, s1 = 0.f;
  int p = beg;
  for (; p + 4 <= end; p += 4) {
    int u0 = idx[p], u1 = idx[p + 1], u2 = idx[p + 2], u3 = idx[p + 3];
    uint v0 = *(const uint*)(in + (size_t)u0 * KF + lane * 2);
    uint v1 = *(const uint*)(in + (size_t)u1 * KF + lane * 2);
    uint v2 = *(const uint*)(in + (size_t)u2 * KF + lane * 2);
    uint v3 = *(const uint*)(in + (size_t)u3 * KF + lane * 2);
    s0 += (b2f(v0 & 0xffffu) + b2f(v1 & 0xffffu)) + (b2f(v2 & 0xffffu) + b2f(v3 & 0xffffu));
    s1 += (b2f(v0 >> 16) + b2f(v1 >> 16)) + (b2f(v2 >> 16) + b2f(v3 >> 16));
  }
  for (; p < end; ++p) {
    int u0 = idx[p];
    uint v0 = *(const uint*)(in + (size_t)u0 * KF + lane * 2);
    s0 += b2f(v0 & 0xffffu);
    s1 += b2f(v0 >> 16);
  }
  float w = wout[wid];
  uint o = (uint)f2b(s0 * w) | ((uint)f2b(s1 * w) << 16);
  *(uint*)(out + (size_t)wid * KF + lane * 2) = o;
}

// ---------------- MFMA GEMM, no LDS: wave holds all A-frags in regs ----------------
// block = 4 waves, 64 rows; wave w -> rows blk*64 + w*16, all NCT*16 cols.
// EPI 0: outb = bf16(max(prev, acc(+bias)));  outs = bf16(same * ro[row]);
//        prev = NORMP ? relu(h*a+b) : h
// EPI 1: outf fp32 = acc   (dual-matmul output, pre-norm h)
// EPI 2: outf fp32 (N=NCLS) = acc + bias     (final layer)
template <int NCT, bool DUAL, int EPI, bool HASB, bool NORMP>
__global__ __launch_bounds__(256) void k_gemm(
    const ushort* __restrict__ A1, const ushort* __restrict__ Wt1,
    const ushort* __restrict__ A2, const ushort* __restrict__ Wt2,
    const float* __restrict__ bias, const float* __restrict__ hprev,
    const float* __restrict__ ab, const float* __restrict__ rosc,
    float* __restrict__ outf, ushort* __restrict__ outb, ushort* __restrict__ outs) {
  int lane = threadIdx.x & 63;
  int w = threadIdx.x >> 6;
  int r0 = blockIdx.x * 64 + w * 16;
  int arow = r0 + (lane & 15);
  if (arow > NN - 1) arow = NN - 1;
  int k0 = (lane >> 4) * 8;

  bf16x8 a1[4], a2[4];
#pragma unroll
  for (int ks = 0; ks < 4; ++ks) {
    a1[ks] = *(const bf16x8*)(A1 + (size_t)arow * KF + ks * 32 + k0);
    if (DUAL) a2[ks] = *(const bf16x8*)(A2 + (size_t)arow * KF + ks * 32 + k0);
  }
  f32x4 acc[NCT];
#pragma unroll
  for (int ct = 0; ct < NCT; ++ct) acc[ct] = (f32x4){0.f, 0.f, 0.f, 0.f};

#pragma unroll
  for (int ks = 0; ks < 4; ++ks) {
#pragma unroll
    for (int ct = 0; ct < NCT; ++ct) {
      int ncol = ct * 16 + (lane & 15);
      if (EPI == 2 && ncol > NCLS - 1) ncol = NCLS - 1;
      bf16x8 b1 = *(const bf16x8*)(Wt1 + (size_t)ncol * KF + ks * 32 + k0);
      acc[ct] = __builtin_amdgcn_mfma_f32_16x16x32_bf16(a1[ks], b1, acc[ct], 0, 0, 0);
      if (DUAL) {
        bf16x8 b2 = *(const bf16x8*)(Wt2 + (size_t)ncol * KF + ks * 32 + k0);
        acc[ct] = __builtin_amdgcn_mfma_f32_16x16x32_bf16(a2[ks], b2, acc[ct], 0, 0, 0);
      }
    }
  }

  int rbase = r0 + (lane >> 4) * 4;
  float rsc[4];
  if (EPI == 0) {
#pragma unroll
    for (int j = 0; j < 4; ++j) rsc[j] = rosc[min(rbase + j, NN - 1)];
  }
#pragma unroll
  for (int ct = 0; ct < NCT; ++ct) {
    int col = ct * 16 + (lane & 15);
#pragma unroll
    for (int j = 0; j < 4; ++j) {
      int rr = rbase + j;
      if (rr >= NN) continue;
      float v = acc[ct][j];
      if (EPI == 0) {
        if (HASB) v += bias[col];
        float p = hprev[(size_t)rr * KF + col];
        if (NORMP) p = fmaxf(0.f, p * ab[col] + ab[KF + col]);
        float hv = fmaxf(p, v);
        outb[(size_t)rr * KF + col] = f2b(hv);
        outs[(size_t)rr * KF + col] = f2b(hv * rsc[j]);
      } else if (EPI == 1) {
        outf[(size_t)rr * KF + col] = v;
      } else {
        if (col < NCLS) outf[(size_t)rr * NCLS + col] = v + bias[col];
      }
    }
  }
}

// ---------------- column stats (mean/var over rows) on fp32 h ----------------
__global__ __launch_bounds__(256) void k_stats_part(const float* __restrict__ C, float* __restrict__ part) {
  int b = blockIdx.x;
  int col = threadIdx.x & 127;
  int half = threadIdx.x >> 7;
  const int chunk = (NN + 511) / 512;
  int rbeg = b * chunk;
  int rend = rbeg + chunk;
  if (rend > NN) rend = NN;
  float s = 0.f, q = 0.f;
  for (int r = rbeg + half; r < rend; r += 2) {
    float v = C[(size_t)r * KF + col];
    s += v;
    q += v * v;
  }
  __shared__ float sm[256], qm[256];
  sm[threadIdx.x] = s;
  qm[threadIdx.x] = q;
  __syncthreads();
  if (half == 0) {
    part[b * 256 + col] = sm[col] + sm[col + 128];
    part[b * 256 + 128 + col] = qm[col] + qm[col + 128];
  }
}

__global__ void k_stats_fin(const float* __restrict__ part, const float* __restrict__ gamma,
                            const float* __restrict__ beta, float* __restrict__ ab) {
  int c = threadIdx.x;  // 128 threads
  float s = 0.f, q = 0.f;
  for (int b = 0; b < 512; ++b) {
    s += part[b * 256 + c];
    q += part[b * 256 + 128 + c];
  }
  float mu = s / (float)NN;
  float var = q / (float)NN - mu * mu;
  float rs = rsqrtf(var + EPSV);
  float a = gamma[c] * rs;
  ab[c] = a;
  ab[KF + c] = beta[c] - mu * a;
}

extern "C" void kernel_launch(void* const* d_in, const int* in_sizes, int n_in,
                              void* d_out, int out_size, void* d_ws, size_t ws_size,
                              hipStream_t stream) {
  const float* feat  = (const float*)d_in[0];
  const float* Wb    = (const float*)d_in[1];   // 3x128x128
  const float* bb2   = (const float*)d_in[2];   // 128
  const float* Wh01  = (const float*)d_in[3];   // 2x128x128
  const float* W2    = (const float*)d_in[4];   // 128x40
  const float* b2    = (const float*)d_in[5];   // 40
  const float* Wl01  = (const float*)d_in[6];   // 2x128x128
  const float* Wl2   = (const float*)d_in[7];   // 128x40
  const float* gamma = (const float*)d_in[8];   // 2x128
  const float* beta  = (const float*)d_in[9];   // 2x128
  const int* src = (const int*)d_in[10];
  const int* dst = (const int*)d_in[11];
  float* out = (float*)d_out;

  char* ws = (char*)d_ws;
  size_t off = 0;
  auto alloc = [&](size_t b) { size_t o = off; off += (b + 255) & ~(size_t)255; return o; };
  size_t z0 = alloc((size_t)2 * NN * 4);  // deg_out|deg_in (one memset)
  int* deg_out = (int*)(ws + z0);
  int* deg_in = deg_out + NN;
  int* ptr_f = (int*)(ws + alloc((size_t)(NN + 1) * 4));
  int* ptr_r = (int*)(ws + alloc((size_t)(NN + 1) * 4));
  int* idx_f = (int*)(ws + alloc((size_t)NE * 4));
  int* idx_r = (int*)(ws + alloc((size_t)NE * 4));
  uint* rank = (uint*)(ws + alloc((size_t)NE * 4));
  float* ro = (float*)(ws + alloc((size_t)NN * 4));
  float* ri = (float*)(ws + alloc((size_t)NN * 4));
  ushort* featb = (ushort*)(ws + alloc((size_t)NN * KF * 2));  // also reused as t1b
  ushort* aggb  = (ushort*)(ws + alloc((size_t)NN * KF * 2));
  ushort* hmaxb = (ushort*)(ws + alloc((size_t)NN * KF * 2));
  ushort* hmaxs = (ushort*)(ws + alloc((size_t)NN * KF * 2));
  float* hbuf = (float*)(ws + alloc((size_t)NN * KF * 4));
  float* part = (float*)(ws + alloc((size_t)512 * 256 * 4));
  float* ab = (float*)(ws + alloc((size_t)256 * 4));
  ushort* wt = (ushort*)(ws + alloc((size_t)(WT_L2 + NCLS * KF) * 2));
  ushort* t1b = featb;  // featb dead after reverse SpMM
  (void)ws_size;

  hipMemsetAsync(ws + z0, 0, (size_t)2 * NN * 4, stream);
  int eb = (NE + 255) / 256;
  k_deg<<<eb, 256, 0, stream>>>(src, dst, deg_out, deg_in, rank);
  k_scan<<<1, 1024, 0, stream>>>(deg_in, ptr_f);
  k_scan<<<1, 1024, 0, stream>>>(deg_out, ptr_r);
  k_rsq<<<(NN + 255) / 256, 256, 0, stream>>>(deg_out, deg_in, ro, ri);
  k_scatter<<<eb, 256, 0, stream>>>(src, dst, ptr_f, ptr_r, rank, idx_f, idx_r);
  k_convW<<<(WT_L2 + NCLS * KF + 255) / 256, 256, 0, stream>>>(Wb, Wh01, Wl01, W2, Wl2, wt);
  k_convF<<<NN * KF / 8 / 256, 256, 0, stream>>>(feat, ri, featb);

  const ushort* wtB[3] = {wt, wt + 16384, wt + 2 * 16384};
  const ushort* wtH[2] = {wt + 3 * 16384, wt + 4 * 16384};
  const ushort* wtL[2] = {wt + 5 * 16384, wt + 6 * 16384};
  const ushort* wtW2 = wt + WT_W2;
  const ushort* wtL2 = wt + WT_L2;

  int sb = (NN * 64 + 255) / 256;  // one wave per row
  // reverse conv SpMM once: aggb[u] = ro[u] * sum_{u->d} (feat*ri)[d]
  k_spmm_b<<<sb, 256, 0, stream>>>(featb, ptr_r, idx_r, ro, aggb);

  int mb = (NN + 63) / 64;
  // ---- layer 0 ----
  k_gemm<8, false, 0, false, false><<<mb, 256, 0, stream>>>(
      aggb, wtB[0], nullptr, nullptr, nullptr, feat, nullptr, ro, nullptr, hmaxb, hmaxs);
  k_spmm_b<<<sb, 256, 0, stream>>>(hmaxs, ptr_f, idx_f, ri, t1b);
  k_gemm<8, true, 1, false, false><<<mb, 256, 0, stream>>>(
      t1b, wtH[0], hmaxb, wtL[0], nullptr, nullptr, nullptr, nullptr, hbuf, nullptr, nullptr);
  k_stats_part<<<512, 256, 0, stream>>>(hbuf, part);
  k_stats_fin<<<1, 128, 0, stream>>>(part, gamma, beta, ab);
  // ---- layer 1 ----  (norm of hbuf folded into hprev read via ab)
  k_gemm<8, false, 0, false, true><<<mb, 256, 0, stream>>>(
      aggb, wtB[1], nullptr, nullptr, nullptr, hbuf, ab, ro, nullptr, hmaxb, hmaxs);
  k_spmm_b<<<sb, 256, 0, stream>>>(hmaxs, ptr_f, idx_f, ri, t1b);
  k_gemm<8, true, 1, false, false><<<mb, 256, 0, stream>>>(
      t1b, wtH[1], hmaxb, wtL[1], nullptr, nullptr, nullptr, nullptr, hbuf, nullptr, nullptr);
  k_stats_part<<<512, 256, 0, stream>>>(hbuf, part);
  k_stats_fin<<<1, 128, 0, stream>>>(part, gamma + KF, beta + KF, ab);
  // ---- layer 2 ----
  k_gemm<8, false, 0, true, true><<<mb, 256, 0, stream>>>(
      aggb, wtB[2], nullptr, nullptr, bb2, hbuf, ab, ro, nullptr, hmaxb, hmaxs);
  k_spmm_b<<<sb, 256, 0, stream>>>(hmaxs, ptr_f, idx_f, ri, t1b);
  k_gemm<3, true, 2, false, false><<<mb, 256, 0, stream>>>(
      t1b, wtW2, hmaxb, wtL2, b2, nullptr, nullptr, nullptr, out, nullptr, nullptr);
}

// Round 6
// 1029.471 us; speedup vs baseline: 2.0604x; 1.3575x over previous
//
#include <hip/hip_runtime.h>

#define NN 100000
#define NE 1600000
#define KF 128
#define NCLS 40
#define EPSV 1e-5f
#define SCAN_NB ((NN + 1023) / 1024)  // 98 blocks of 1024 elems

typedef short bf16x8 __attribute__((ext_vector_type(8)));
typedef float f32x4 __attribute__((ext_vector_type(4)));
typedef unsigned short ushort;
typedef unsigned int uint;
typedef ushort ush8 __attribute__((ext_vector_type(8)));

static __device__ __forceinline__ int imax1(int x) { return x > 0 ? x : 1; }

static __device__ __forceinline__ ushort f2b(float f) {  // fp32 -> bf16 RNE
  uint u = __builtin_bit_cast(uint, f);
  u += 0x7fffu + ((u >> 16) & 1u);
  return (ushort)(u >> 16);
}
static __device__ __forceinline__ float b2f(uint bits16) {
  return __builtin_bit_cast(float, bits16 << 16);
}

// ---------------- graph build ----------------
// degrees via atomics; atomic return value IS the edge's rank within its CSR row
__global__ void k_deg(const int* __restrict__ src, const int* __restrict__ dst,
                      int* __restrict__ deg_out, int* __restrict__ deg_in,
                      uint* __restrict__ rank) {
  int e = blockIdx.x * blockDim.x + threadIdx.x;
  if (e < NE) {
    int rs = atomicAdd(&deg_out[src[e]], 1);  // rank in reverse-CSR row src
    int rd = atomicAdd(&deg_in[dst[e]], 1);   // rank in forward-CSR row dst
    rank[e] = ((uint)rd << 16) | (uint)rs;
  }
}

// ---- 3-phase device-wide exclusive scan of BOTH degree arrays ----
// blocks [0, SCAN_NB): deg_in -> ptr_f ; [SCAN_NB, 2*SCAN_NB): deg_out -> ptr_r
__global__ __launch_bounds__(256) void k_scan_part(const int* __restrict__ deg_in,
                                                   const int* __restrict__ deg_out,
                                                   int* __restrict__ bsum) {
  int arr = (int)(blockIdx.x >= SCAN_NB);
  const int* deg = arr ? deg_out : deg_in;
  int b = blockIdx.x - arr * SCAN_NB;
  int base = b * 1024 + threadIdx.x * 4;
  int4 v = {0, 0, 0, 0};
  if (base < NN) v = *(const int4*)(deg + base);  // NN%4==0: all-in or all-out
  int s = v.x + v.y + v.z + v.w;
  __shared__ int sm[256];
  sm[threadIdx.x] = s;
  __syncthreads();
  for (int d = 128; d > 0; d >>= 1) {
    if (threadIdx.x < d) sm[threadIdx.x] += sm[threadIdx.x + d];
    __syncthreads();
  }
  if (threadIdx.x == 0) bsum[blockIdx.x] = sm[0];
}

__global__ __launch_bounds__(256) void k_scan_mid(int* __restrict__ bsum) {
  __shared__ int sm[2][128];
  int t = threadIdx.x & 127;
  int seg = threadIdx.x >> 7;
  int v = (t < SCAN_NB) ? bsum[seg * SCAN_NB + t] : 0;
  sm[seg][t] = v;
  __syncthreads();
  for (int d = 1; d < 128; d <<= 1) {
    int x = (t >= d) ? sm[seg][t - d] : 0;
    __syncthreads();
    sm[seg][t] += x;
    __syncthreads();
  }
  if (t < SCAN_NB) bsum[seg * SCAN_NB + t] = sm[seg][t] - v;  // exclusive
}

__global__ __launch_bounds__(256) void k_scan_out(const int* __restrict__ deg_in,
                                                  const int* __restrict__ deg_out,
                                                  const int* __restrict__ bsum,
                                                  int* __restrict__ ptr_f, int* __restrict__ ptr_r) {
  int arr = (int)(blockIdx.x >= SCAN_NB);
  const int* deg = arr ? deg_out : deg_in;
  int* ptr = arr ? ptr_r : ptr_f;
  int b = blockIdx.x - arr * SCAN_NB;
  int base = b * 1024 + threadIdx.x * 4;
  int4 v = {0, 0, 0, 0};
  if (base < NN) v = *(const int4*)(deg + base);
  int s = v.x + v.y + v.z + v.w;
  __shared__ int sm[256];
  sm[threadIdx.x] = s;
  __syncthreads();
  for (int d = 1; d < 256; d <<= 1) {
    int x = (threadIdx.x >= d) ? sm[threadIdx.x - d] : 0;
    __syncthreads();
    sm[threadIdx.x] += x;
    __syncthreads();
  }
  int off = bsum[blockIdx.x] + sm[threadIdx.x] - s;  // exclusive across block
  if (base < NN) {
    int4 o;
    o.x = off;
    o.y = off + v.x;
    o.z = off + v.x + v.y;
    o.w = off + v.x + v.y + v.z;
    *(int4*)(ptr + base) = o;
  }
  if (blockIdx.x == 0 && threadIdx.x == 0) { ptr_f[NN] = NE; ptr_r[NN] = NE; }
}

__global__ void k_rsq(const int* __restrict__ deg_out, const int* __restrict__ deg_in,
                      float* __restrict__ ro, float* __restrict__ ri) {
  int i = blockIdx.x * blockDim.x + threadIdx.x;
  if (i < NN) {
    ro[i] = rsqrtf((float)imax1(deg_out[i]));
    ri[i] = rsqrtf((float)imax1(deg_in[i]));
  }
}

// atomic-free scatter using precomputed ranks
__global__ void k_scatter(const int* __restrict__ src, const int* __restrict__ dst,
                          const int* __restrict__ ptr_f, const int* __restrict__ ptr_r,
                          const uint* __restrict__ rank,
                          int* __restrict__ idx_f, int* __restrict__ idx_r) {
  int e = blockIdx.x * blockDim.x + threadIdx.x;
  if (e < NE) {
    int s = src[e], d = dst[e];
    uint rk = rank[e];
    idx_f[ptr_f[d] + (int)(rk >> 16)] = s;
    idx_r[ptr_r[s] + (int)(rk & 0xffffu)] = d;
  }
}

// ---------------- fp32 -> bf16 convert, row-scaled by ri (rev-SpMM pre-scale) ----------------
__global__ __launch_bounds__(256) void k_convF(const float* __restrict__ in, const float* __restrict__ ri,
                       ushort* __restrict__ out) {
  int t = blockIdx.x * blockDim.x + threadIdx.x;
  int i = t * 8;  // grid sized exactly; 16 threads per row
  float w = ri[t >> 4];
  float4 a = *(const float4*)(in + i);
  float4 b = *(const float4*)(in + i + 4);
  ush8 o;
  o[0] = f2b(a.x * w); o[1] = f2b(a.y * w); o[2] = f2b(a.z * w); o[3] = f2b(a.w * w);
  o[4] = f2b(b.x * w); o[5] = f2b(b.y * w); o[6] = f2b(b.z * w); o[7] = f2b(b.w * w);
  *(ush8*)(out + i) = o;
}

// ---------------- weight convert+transpose: wt[n][k] = bf16(W[k][n]) ----------------
// layout: [0..3)x16384 Wb | [3..5)x16384 Wh01 | [5..7)x16384 Wl01 | 40x128 W2 | 40x128 Wl2
#define WT_W2 (7 * 16384)
#define WT_L2 (WT_W2 + NCLS * KF)
__global__ __launch_bounds__(256) void k_convW(const float* __restrict__ Wb, const float* __restrict__ Wh01,
                       const float* __restrict__ Wl01, const float* __restrict__ W2,
                       const float* __restrict__ Wl2, ushort* __restrict__ wt) {
  int i = blockIdx.x * blockDim.x + threadIdx.x;  // grid sized exactly (124928)
  float v;
  if (i < WT_W2) {
    int m = i >> 14, r = (i >> 7) & 127, k = i & 127;
    const float* srcm = (m < 3) ? (Wb + m * 16384)
                      : (m < 5) ? (Wh01 + (m - 3) * 16384)
                                : (Wl01 + (m - 5) * 16384);
    v = srcm[k * KF + r];
  } else {
    int j = i - WT_W2;
    int m2 = j / (NCLS * KF);
    int t = j - m2 * (NCLS * KF);
    int n = t >> 7, k = t & 127;
    v = (m2 ? Wl2 : W2)[k * NCLS + n];
  }
  wt[i] = f2b(v);
}

// ---------------- SpMM (pre-scaled rows): out[v] = wout[v] * sum_{u in row v} in[u] ----------------
// one wave per row; lane handles 2 bf16 (uint); unroll 4 edges for MLP
__global__ __launch_bounds__(256) void k_spmm_b(const ushort* __restrict__ in,
                      const int* __restrict__ ptr, const int* __restrict__ idx,
                      const float* __restrict__ wout, ushort* __restrict__ out) {
  int wid = (blockIdx.x * blockDim.x + threadIdx.x) >> 6;
  int lane = threadIdx.x & 63;
  if (wid >= NN) return;
  int beg = ptr[wid], end = ptr[wid + 1];
  float s0 = 0.f, s1 = 0.f;
  int p = beg;
  for (; p + 4 <= end; p += 4) {
    int u0 = idx[p], u1 = idx[p + 1], u2 = idx[p + 2], u3 = idx[p + 3];
    uint v0 = *(const uint*)(in + (size_t)u0 * KF + lane * 2);
    uint v1 = *(const uint*)(in + (size_t)u1 * KF + lane * 2);
    uint v2 = *(const uint*)(in + (size_t)u2 * KF + lane * 2);
    uint v3 = *(const uint*)(in + (size_t)u3 * KF + lane * 2);
    s0 += (b2f(v0 & 0xffffu) + b2f(v1 & 0xffffu)) + (b2f(v2 & 0xffffu) + b2f(v3 & 0xffffu));
    s1 += (b2f(v0 >> 16) + b2f(v1 >> 16)) + (b2f(v2 >> 16) + b2f(v3 >> 16));
  }
  for (; p < end; ++p) {
    int u0 = idx[p];
    uint v0 = *(const uint*)(in + (size_t)u0 * KF + lane * 2);
    s0 += b2f(v0 & 0xffffu);
    s1 += b2f(v0 >> 16);
  }
  float w = wout[wid];
  uint o = (uint)f2b(s0 * w) | ((uint)f2b(s1 * w) << 16);
  *(uint*)(out + (size_t)wid * KF + lane * 2) = o;
}

// ---------------- MFMA GEMM, no LDS: wave holds all A-frags in regs ----------------
// block = 4 waves, 64 rows; wave w -> rows blk*64 + w*16, all NCT*16 cols.
// EPI 0: outb = bf16(max(prev, acc(+bias)));  outs = bf16(same * ro[row]);
//        prev = NORMP ? relu(h*a+b) : h
// EPI 1: outf fp32 = acc   (dual-matmul output, pre-norm h)
// EPI 2: outf fp32 (N=NCLS) = acc + bias     (final layer)
template <int NCT, bool DUAL, int EPI, bool HASB, bool NORMP>
__global__ __launch_bounds__(256) void k_gemm(
    const ushort* __restrict__ A1, const ushort* __restrict__ Wt1,
    const ushort* __restrict__ A2, const ushort* __restrict__ Wt2,
    const float* __restrict__ bias, const float* __restrict__ hprev,
    const float* __restrict__ ab, const float* __restrict__ rosc,
    float* __restrict__ outf, ushort* __restrict__ outb, ushort* __restrict__ outs) {
  int lane = threadIdx.x & 63;
  int w = threadIdx.x >> 6;
  int r0 = blockIdx.x * 64 + w * 16;
  int arow = r0 + (lane & 15);
  if (arow > NN - 1) arow = NN - 1;
  int k0 = (lane >> 4) * 8;

  bf16x8 a1[4], a2[4];
#pragma unroll
  for (int ks = 0; ks < 4; ++ks) {
    a1[ks] = *(const bf16x8*)(A1 + (size_t)arow * KF + ks * 32 + k0);
    if (DUAL) a2[ks] = *(const bf16x8*)(A2 + (size_t)arow * KF + ks * 32 + k0);
  }
  f32x4 acc[NCT];
#pragma unroll
  for (int ct = 0; ct < NCT; ++ct) acc[ct] = (f32x4){0.f, 0.f, 0.f, 0.f};

#pragma unroll
  for (int ks = 0; ks < 4; ++ks) {
#pragma unroll
    for (int ct = 0; ct < NCT; ++ct) {
      int ncol = ct * 16 + (lane & 15);
      if (EPI == 2 && ncol > NCLS - 1) ncol = NCLS - 1;
      bf16x8 b1 = *(const bf16x8*)(Wt1 + (size_t)ncol * KF + ks * 32 + k0);
      acc[ct] = __builtin_amdgcn_mfma_f32_16x16x32_bf16(a1[ks], b1, acc[ct], 0, 0, 0);
      if (DUAL) {
        bf16x8 b2 = *(const bf16x8*)(Wt2 + (size_t)ncol * KF + ks * 32 + k0);
        acc[ct] = __builtin_amdgcn_mfma_f32_16x16x32_bf16(a2[ks], b2, acc[ct], 0, 0, 0);
      }
    }
  }

  int rbase = r0 + (lane >> 4) * 4;
  float rsc[4];
  if (EPI == 0) {
#pragma unroll
    for (int j = 0; j < 4; ++j) rsc[j] = rosc[min(rbase + j, NN - 1)];
  }
#pragma unroll
  for (int ct = 0; ct < NCT; ++ct) {
    int col = ct * 16 + (lane & 15);
#pragma unroll
    for (int j = 0; j < 4; ++j) {
      int rr = rbase + j;
      if (rr >= NN) continue;
      float v = acc[ct][j];
      if (EPI == 0) {
        if (HASB) v += bias[col];
        float p = hprev[(size_t)rr * KF + col];
        if (NORMP) p = fmaxf(0.f, p * ab[col] + ab[KF + col]);
        float hv = fmaxf(p, v);
        outb[(size_t)rr * KF + col] = f2b(hv);
        outs[(size_t)rr * KF + col] = f2b(hv * rsc[j]);
      } else if (EPI == 1) {
        outf[(size_t)rr * KF + col] = v;
      } else {
        if (col < NCLS) outf[(size_t)rr * NCLS + col] = v + bias[col];
      }
    }
  }
}

// ---------------- column stats (mean/var over rows) on fp32 h ----------------
__global__ __launch_bounds__(256) void k_stats_part(const float* __restrict__ C, float* __restrict__ part) {
  int b = blockIdx.x;
  int col = threadIdx.x & 127;
  int half = threadIdx.x >> 7;
  const int chunk = (NN + 511) / 512;
  int rbeg = b * chunk;
  int rend = rbeg + chunk;
  if (rend > NN) rend = NN;
  float s = 0.f, q = 0.f;
  for (int r = rbeg + half; r < rend; r += 2) {
    float v = C[(size_t)r * KF + col];
    s += v;
    q += v * v;
  }
  __shared__ float sm[256], qm[256];
  sm[threadIdx.x] = s;
  qm[threadIdx.x] = q;
  __syncthreads();
  if (half == 0) {
    part[b * 256 + col] = sm[col] + sm[col + 128];
    part[b * 256 + 128 + col] = qm[col] + qm[col + 128];
  }
}

__global__ void k_stats_fin(const float* __restrict__ part, const float* __restrict__ gamma,
                            const float* __restrict__ beta, float* __restrict__ ab) {
  int c = threadIdx.x;  // 128 threads
  float s = 0.f, q = 0.f;
  for (int b = 0; b < 512; ++b) {
    s += part[b * 256 + c];
    q += part[b * 256 + 128 + c];
  }
  float mu = s / (float)NN;
  float var = q / (float)NN - mu * mu;
  float rs = rsqrtf(var + EPSV);
  float a = gamma[c] * rs;
  ab[c] = a;
  ab[KF + c] = beta[c] - mu * a;
}

extern "C" void kernel_launch(void* const* d_in, const int* in_sizes, int n_in,
                              void* d_out, int out_size, void* d_ws, size_t ws_size,
                              hipStream_t stream) {
  const float* feat  = (const float*)d_in[0];
  const float* Wb    = (const float*)d_in[1];   // 3x128x128
  const float* bb2   = (const float*)d_in[2];   // 128
  const float* Wh01  = (const float*)d_in[3];   // 2x128x128
  const float* W2    = (const float*)d_in[4];   // 128x40
  const float* b2    = (const float*)d_in[5];   // 40
  const float* Wl01  = (const float*)d_in[6];   // 2x128x128
  const float* Wl2   = (const float*)d_in[7];   // 128x40
  const float* gamma = (const float*)d_in[8];   // 2x128
  const float* beta  = (const float*)d_in[9];   // 2x128
  const int* src = (const int*)d_in[10];
  const int* dst = (const int*)d_in[11];
  float* out = (float*)d_out;

  char* ws = (char*)d_ws;
  size_t off = 0;
  auto alloc = [&](size_t b) { size_t o = off; off += (b + 255) & ~(size_t)255; return o; };
  size_t z0 = alloc((size_t)2 * NN * 4);  // deg_out|deg_in (one memset)
  int* deg_out = (int*)(ws + z0);
  int* deg_in = deg_out + NN;
  int* ptr_f = (int*)(ws + alloc((size_t)(NN + 1) * 4));
  int* ptr_r = (int*)(ws + alloc((size_t)(NN + 1) * 4));
  int* idx_f = (int*)(ws + alloc((size_t)NE * 4));
  int* idx_r = (int*)(ws + alloc((size_t)NE * 4));
  uint* rank = (uint*)(ws + alloc((size_t)NE * 4));
  float* ro = (float*)(ws + alloc((size_t)NN * 4));
  float* ri = (float*)(ws + alloc((size_t)NN * 4));
  int* bsum = (int*)(ws + alloc((size_t)2 * SCAN_NB * 4));
  ushort* featb = (ushort*)(ws + alloc((size_t)NN * KF * 2));  // also reused as t1b
  ushort* aggb  = (ushort*)(ws + alloc((size_t)NN * KF * 2));
  ushort* hmaxb = (ushort*)(ws + alloc((size_t)NN * KF * 2));
  ushort* hmaxs = (ushort*)(ws + alloc((size_t)NN * KF * 2));
  float* hbuf = (float*)(ws + alloc((size_t)NN * KF * 4));
  float* part = (float*)(ws + alloc((size_t)512 * 256 * 4));
  float* ab = (float*)(ws + alloc((size_t)256 * 4));
  ushort* wt = (ushort*)(ws + alloc((size_t)(WT_L2 + NCLS * KF) * 2));
  ushort* t1b = featb;  // featb dead after reverse SpMM
  (void)ws_size;

  hipMemsetAsync(ws + z0, 0, (size_t)2 * NN * 4, stream);
  int eb = (NE + 255) / 256;
  k_deg<<<eb, 256, 0, stream>>>(src, dst, deg_out, deg_in, rank);
  k_scan_part<<<2 * SCAN_NB, 256, 0, stream>>>(deg_in, deg_out, bsum);
  k_scan_mid<<<1, 256, 0, stream>>>(bsum);
  k_scan_out<<<2 * SCAN_NB, 256, 0, stream>>>(deg_in, deg_out, bsum, ptr_f, ptr_r);
  k_rsq<<<(NN + 255) / 256, 256, 0, stream>>>(deg_out, deg_in, ro, ri);
  k_scatter<<<eb, 256, 0, stream>>>(src, dst, ptr_f, ptr_r, rank, idx_f, idx_r);
  k_convW<<<(WT_L2 + NCLS * KF + 255) / 256, 256, 0, stream>>>(Wb, Wh01, Wl01, W2, Wl2, wt);
  k_convF<<<NN * KF / 8 / 256, 256, 0, stream>>>(feat, ri, featb);

  const ushort* wtB[3] = {wt, wt + 16384, wt + 2 * 16384};
  const ushort* wtH[2] = {wt + 3 * 16384, wt + 4 * 16384};
  const ushort* wtL[2] = {wt + 5 * 16384, wt + 6 * 16384};
  const ushort* wtW2 = wt + WT_W2;
  const ushort* wtL2 = wt + WT_L2;

  int sb = (NN * 64 + 255) / 256;  // one wave per row
  // reverse conv SpMM once: aggb[u] = ro[u] * sum_{u->d} (feat*ri)[d]
  k_spmm_b<<<sb, 256, 0, stream>>>(featb, ptr_r, idx_r, ro, aggb);

  int mb = (NN + 63) / 64;
  // ---- layer 0 ----
  k_gemm<8, false, 0, false, false><<<mb, 256, 0, stream>>>(
      aggb, wtB[0], nullptr, nullptr, nullptr, feat, nullptr, ro, nullptr, hmaxb, hmaxs);
  k_spmm_b<<<sb, 256, 0, stream>>>(hmaxs, ptr_f, idx_f, ri, t1b);
  k_gemm<8, true, 1, false, false><<<mb, 256, 0, stream>>>(
      t1b, wtH[0], hmaxb, wtL[0], nullptr, nullptr, nullptr, nullptr, hbuf, nullptr, nullptr);
  k_stats_part<<<512, 256, 0, stream>>>(hbuf, part);
  k_stats_fin<<<1, 128, 0, stream>>>(part, gamma, beta, ab);
  // ---- layer 1 ----  (norm of hbuf folded into hprev read via ab)
  k_gemm<8, false, 0, false, true><<<mb, 256, 0, stream>>>(
      aggb, wtB[1], nullptr, nullptr, nullptr, hbuf, ab, ro, nullptr, hmaxb, hmaxs);
  k_spmm_b<<<sb, 256, 0, stream>>>(hmaxs, ptr_f, idx_f, ri, t1b);
  k_gemm<8, true, 1, false, false><<<mb, 256, 0, stream>>>(
      t1b, wtH[1], hmaxb, wtL[1], nullptr, nullptr, nullptr, nullptr, hbuf, nullptr, nullptr);
  k_stats_part<<<512, 256, 0, stream>>>(hbuf, part);
  k_stats_fin<<<1, 128, 0, stream>>>(part, gamma + KF, beta + KF, ab);
  // ---- layer 2 ----
  k_gemm<8, false, 0, true, true><<<mb, 256, 0, stream>>>(
      aggb, wtB[2], nullptr, nullptr, bb2, hbuf, ab, ro, nullptr, hmaxb, hmaxs);
  k_spmm_b<<<sb, 256, 0, stream>>>(hmaxs, ptr_f, idx_f, ri, t1b);
  k_gemm<3, true, 2, false, false><<<mb, 256, 0, stream>>>(
      t1b, wtW2, hmaxb, wtL2, b2, nullptr, nullptr, nullptr, out, nullptr, nullptr);
}

// Round 7
// 885.284 us; speedup vs baseline: 2.3960x; 1.1629x over previous
//
#include <hip/hip_runtime.h>

#define NN 100000
#define NE 1600000
#define KF 128
#define NCLS 40
#define EPSV 1e-5f
#define SCAN_NB ((NN + 1023) / 1024)  // 98 blocks of 1024 elems

typedef short bf16x8 __attribute__((ext_vector_type(8)));
typedef float f32x4 __attribute__((ext_vector_type(4)));
typedef unsigned short ushort;
typedef unsigned int uint;
typedef ushort ush8 __attribute__((ext_vector_type(8)));

static __device__ __forceinline__ int imax1(int x) { return x > 0 ? x : 1; }

static __device__ __forceinline__ ushort f2b(float f) {  // fp32 -> bf16 RNE
  uint u = __builtin_bit_cast(uint, f);
  u += 0x7fffu + ((u >> 16) & 1u);
  return (ushort)(u >> 16);
}
static __device__ __forceinline__ float b2f(uint bits16) {
  return __builtin_bit_cast(float, bits16 << 16);
}

// ---------------- graph build ----------------
// degrees via atomics; atomic return value IS the edge's rank within its CSR row
__global__ void k_deg(const int* __restrict__ src, const int* __restrict__ dst,
                      int* __restrict__ deg_out, int* __restrict__ deg_in,
                      uint* __restrict__ rank) {
  int e = blockIdx.x * blockDim.x + threadIdx.x;
  if (e < NE) {
    int rs = atomicAdd(&deg_out[src[e]], 1);  // rank in reverse-CSR row src
    int rd = atomicAdd(&deg_in[dst[e]], 1);   // rank in forward-CSR row dst
    rank[e] = ((uint)rd << 16) | (uint)rs;
  }
}

// ---- 3-phase device-wide exclusive scan of BOTH degree arrays ----
// blocks [0, SCAN_NB): deg_in -> ptr_f ; [SCAN_NB, 2*SCAN_NB): deg_out -> ptr_r
__global__ __launch_bounds__(256) void k_scan_part(const int* __restrict__ deg_in,
                                                   const int* __restrict__ deg_out,
                                                   int* __restrict__ bsum) {
  int arr = (int)(blockIdx.x >= SCAN_NB);
  const int* deg = arr ? deg_out : deg_in;
  int b = blockIdx.x - arr * SCAN_NB;
  int base = b * 1024 + threadIdx.x * 4;
  int4 v = {0, 0, 0, 0};
  if (base < NN) v = *(const int4*)(deg + base);  // NN%4==0: all-in or all-out
  int s = v.x + v.y + v.z + v.w;
  __shared__ int sm[256];
  sm[threadIdx.x] = s;
  __syncthreads();
  for (int d = 128; d > 0; d >>= 1) {
    if (threadIdx.x < d) sm[threadIdx.x] += sm[threadIdx.x + d];
    __syncthreads();
  }
  if (threadIdx.x == 0) bsum[blockIdx.x] = sm[0];
}

__global__ __launch_bounds__(256) void k_scan_mid(int* __restrict__ bsum) {
  __shared__ int sm[2][128];
  int t = threadIdx.x & 127;
  int seg = threadIdx.x >> 7;
  int v = (t < SCAN_NB) ? bsum[seg * SCAN_NB + t] : 0;
  sm[seg][t] = v;
  __syncthreads();
  for (int d = 1; d < 128; d <<= 1) {
    int x = (t >= d) ? sm[seg][t - d] : 0;
    __syncthreads();
    sm[seg][t] += x;
    __syncthreads();
  }
  if (t < SCAN_NB) bsum[seg * SCAN_NB + t] = sm[seg][t] - v;  // exclusive
}

__global__ __launch_bounds__(256) void k_scan_out(const int* __restrict__ deg_in,
                                                  const int* __restrict__ deg_out,
                                                  const int* __restrict__ bsum,
                                                  int* __restrict__ ptr_f, int* __restrict__ ptr_r) {
  int arr = (int)(blockIdx.x >= SCAN_NB);
  const int* deg = arr ? deg_out : deg_in;
  int* ptr = arr ? ptr_r : ptr_f;
  int b = blockIdx.x - arr * SCAN_NB;
  int base = b * 1024 + threadIdx.x * 4;
  int4 v = {0, 0, 0, 0};
  if (base < NN) v = *(const int4*)(deg + base);
  int s = v.x + v.y + v.z + v.w;
  __shared__ int sm[256];
  sm[threadIdx.x] = s;
  __syncthreads();
  for (int d = 1; d < 256; d <<= 1) {
    int x = (threadIdx.x >= d) ? sm[threadIdx.x - d] : 0;
    __syncthreads();
    sm[threadIdx.x] += x;
    __syncthreads();
  }
  int off = bsum[blockIdx.x] + sm[threadIdx.x] - s;  // exclusive across block
  if (base < NN) {
    int4 o;
    o.x = off;
    o.y = off + v.x;
    o.z = off + v.x + v.y;
    o.w = off + v.x + v.y + v.z;
    *(int4*)(ptr + base) = o;
  }
  if (blockIdx.x == 0 && threadIdx.x == 0) { ptr_f[NN] = NE; ptr_r[NN] = NE; }
}

__global__ void k_rsq(const int* __restrict__ deg_out, const int* __restrict__ deg_in,
                      float* __restrict__ ro, float* __restrict__ ri) {
  int i = blockIdx.x * blockDim.x + threadIdx.x;
  if (i < NN) {
    ro[i] = rsqrtf((float)imax1(deg_out[i]));
    ri[i] = rsqrtf((float)imax1(deg_in[i]));
  }
}

// atomic-free scatter using precomputed ranks
__global__ void k_scatter(const int* __restrict__ src, const int* __restrict__ dst,
                          const int* __restrict__ ptr_f, const int* __restrict__ ptr_r,
                          const uint* __restrict__ rank,
                          int* __restrict__ idx_f, int* __restrict__ idx_r) {
  int e = blockIdx.x * blockDim.x + threadIdx.x;
  if (e < NE) {
    int s = src[e], d = dst[e];
    uint rk = rank[e];
    idx_f[ptr_f[d] + (int)(rk >> 16)] = s;
    idx_r[ptr_r[s] + (int)(rk & 0xffffu)] = d;
  }
}

// ---------------- fp32 -> bf16 convert, row-scaled by ri (rev-SpMM pre-scale) ----------------
__global__ __launch_bounds__(256) void k_convF(const float* __restrict__ in, const float* __restrict__ ri,
                       ushort* __restrict__ out) {
  int t = blockIdx.x * blockDim.x + threadIdx.x;
  int i = t * 8;  // grid sized exactly; 16 threads per row
  float w = ri[t >> 4];
  float4 a = *(const float4*)(in + i);
  float4 b = *(const float4*)(in + i + 4);
  ush8 o;
  o[0] = f2b(a.x * w); o[1] = f2b(a.y * w); o[2] = f2b(a.z * w); o[3] = f2b(a.w * w);
  o[4] = f2b(b.x * w); o[5] = f2b(b.y * w); o[6] = f2b(b.z * w); o[7] = f2b(b.w * w);
  *(ush8*)(out + i) = o;
}

// ---------------- weight convert+transpose: wt[n][k] = bf16(W[k][n]) ----------------
// layout: [0..3)x16384 Wb | [3..5)x16384 Wh01 | [5..7)x16384 Wl01 | 40x128 W2 | 40x128 Wl2
#define WT_W2 (7 * 16384)
#define WT_L2 (WT_W2 + NCLS * KF)
__global__ __launch_bounds__(256) void k_convW(const float* __restrict__ Wb, const float* __restrict__ Wh01,
                       const float* __restrict__ Wl01, const float* __restrict__ W2,
                       const float* __restrict__ Wl2, ushort* __restrict__ wt) {
  int i = blockIdx.x * blockDim.x + threadIdx.x;  // grid sized exactly (124928)
  float v;
  if (i < WT_W2) {
    int m = i >> 14, r = (i >> 7) & 127, k = i & 127;
    const float* srcm = (m < 3) ? (Wb + m * 16384)
                      : (m < 5) ? (Wh01 + (m - 3) * 16384)
                                : (Wl01 + (m - 5) * 16384);
    v = srcm[k * KF + r];
  } else {
    int j = i - WT_W2;
    int m2 = j / (NCLS * KF);
    int t = j - m2 * (NCLS * KF);
    int n = t >> 7, k = t & 127;
    v = (m2 ? Wl2 : W2)[k * NCLS + n];
  }
  wt[i] = f2b(v);
}

// ---------------- SpMM (pre-scaled rows): out[v] = wout[v] * sum_{u in row v} in[u] ----------------
// one wave per row; 4 edge streams per wave (16 lanes x uint4 = 256B per edge);
// unroll 2 => 8 edges in flight; final cross-stream combine via 2 shfl_xor steps
__global__ __launch_bounds__(256) void k_spmm_b(const ushort* __restrict__ in,
                      const int* __restrict__ ptr, const int* __restrict__ idx,
                      const float* __restrict__ wout, ushort* __restrict__ out) {
  int wid = (blockIdx.x * blockDim.x + threadIdx.x) >> 6;
  int lane = threadIdx.x & 63;
  if (wid >= NN) return;
  int beg = ptr[wid], end = ptr[wid + 1];
  int strm = lane >> 4;          // edge stream 0..3
  int c8 = (lane & 15) * 8;      // 8 bf16 columns per lane
  float s[8];
#pragma unroll
  for (int j = 0; j < 8; ++j) s[j] = 0.f;
  int p = beg + strm;
  for (; p + 4 < end; p += 8) {  // edges p and p+4 both valid
    int u0 = idx[p], u1 = idx[p + 4];
    uint4 v0 = *(const uint4*)(in + (size_t)u0 * KF + c8);
    uint4 v1 = *(const uint4*)(in + (size_t)u1 * KF + c8);
    s[0] += b2f(v0.x & 0xffffu) + b2f(v1.x & 0xffffu);
    s[1] += b2f(v0.x >> 16)     + b2f(v1.x >> 16);
    s[2] += b2f(v0.y & 0xffffu) + b2f(v1.y & 0xffffu);
    s[3] += b2f(v0.y >> 16)     + b2f(v1.y >> 16);
    s[4] += b2f(v0.z & 0xffffu) + b2f(v1.z & 0xffffu);
    s[5] += b2f(v0.z >> 16)     + b2f(v1.z >> 16);
    s[6] += b2f(v0.w & 0xffffu) + b2f(v1.w & 0xffffu);
    s[7] += b2f(v0.w >> 16)     + b2f(v1.w >> 16);
  }
  if (p < end) {
    int u0 = idx[p];
    uint4 v0 = *(const uint4*)(in + (size_t)u0 * KF + c8);
    s[0] += b2f(v0.x & 0xffffu);
    s[1] += b2f(v0.x >> 16);
    s[2] += b2f(v0.y & 0xffffu);
    s[3] += b2f(v0.y >> 16);
    s[4] += b2f(v0.z & 0xffffu);
    s[5] += b2f(v0.z >> 16);
    s[6] += b2f(v0.w & 0xffffu);
    s[7] += b2f(v0.w >> 16);
  }
#pragma unroll
  for (int j = 0; j < 8; ++j) {
    s[j] += __shfl_xor(s[j], 16);
    s[j] += __shfl_xor(s[j], 32);
  }
  if (lane < 16) {
    float w = wout[wid];
    ush8 o;
#pragma unroll
    for (int j = 0; j < 8; ++j) o[j] = f2b(s[j] * w);
    *(ush8*)(out + (size_t)wid * KF + c8) = o;
  }
}

// ---------------- MFMA GEMM, no LDS (LDS only for EPI1 stats): wave holds A-frags in regs ----------------
// block = 4 waves, 64 rows; wave w -> rows blk*64 + w*16, all NCT*16 cols.
// EPI 0: outb = bf16(max(prev, acc(+bias)));  outs = bf16(same * ro[row]);
//        prev = NORMP ? relu(bf16(h)*a+b) : fp32 h
// EPI 1: outb = bf16(acc) (pre-norm h) + fused column stats (sum, sumsq) -> atomicAdd(stat)
// EPI 2: outf fp32 (N=NCLS) = acc + bias     (final layer)
template <int NCT, bool DUAL, int EPI, bool HASB, bool NORMP>
__global__ __launch_bounds__(256) void k_gemm(
    const ushort* __restrict__ A1, const ushort* __restrict__ Wt1,
    const ushort* __restrict__ A2, const ushort* __restrict__ Wt2,
    const float* __restrict__ bias, const void* __restrict__ hprev,
    const float* __restrict__ ab, const float* __restrict__ rosc,
    float* __restrict__ outf, ushort* __restrict__ outb, ushort* __restrict__ outs,
    float* __restrict__ stat) {
  int lane = threadIdx.x & 63;
  int w = threadIdx.x >> 6;
  int r0 = blockIdx.x * 64 + w * 16;
  int arow = r0 + (lane & 15);
  if (arow > NN - 1) arow = NN - 1;
  int k0 = (lane >> 4) * 8;

  bf16x8 a1[4], a2[4];
#pragma unroll
  for (int ks = 0; ks < 4; ++ks) {
    a1[ks] = *(const bf16x8*)(A1 + (size_t)arow * KF + ks * 32 + k0);
    if (DUAL) a2[ks] = *(const bf16x8*)(A2 + (size_t)arow * KF + ks * 32 + k0);
  }
  f32x4 acc[NCT];
#pragma unroll
  for (int ct = 0; ct < NCT; ++ct) acc[ct] = (f32x4){0.f, 0.f, 0.f, 0.f};

#pragma unroll
  for (int ks = 0; ks < 4; ++ks) {
#pragma unroll
    for (int ct = 0; ct < NCT; ++ct) {
      int ncol = ct * 16 + (lane & 15);
      if (EPI == 2 && ncol > NCLS - 1) ncol = NCLS - 1;
      bf16x8 b1 = *(const bf16x8*)(Wt1 + (size_t)ncol * KF + ks * 32 + k0);
      acc[ct] = __builtin_amdgcn_mfma_f32_16x16x32_bf16(a1[ks], b1, acc[ct], 0, 0, 0);
      if (DUAL) {
        bf16x8 b2 = *(const bf16x8*)(Wt2 + (size_t)ncol * KF + ks * 32 + k0);
        acc[ct] = __builtin_amdgcn_mfma_f32_16x16x32_bf16(a2[ks], b2, acc[ct], 0, 0, 0);
      }
    }
  }

  int rbase = r0 + (lane >> 4) * 4;
  if constexpr (EPI == 0) {
    float rsc[4];
#pragma unroll
    for (int j = 0; j < 4; ++j) rsc[j] = rosc[min(rbase + j, NN - 1)];
#pragma unroll
    for (int ct = 0; ct < NCT; ++ct) {
      int col = ct * 16 + (lane & 15);
#pragma unroll
      for (int j = 0; j < 4; ++j) {
        int rr = rbase + j;
        if (rr >= NN) continue;
        float v = acc[ct][j];
        if (HASB) v += bias[col];
        float p;
        if (NORMP)
          p = fmaxf(0.f, b2f((uint)((const ushort*)hprev)[(size_t)rr * KF + col]) * ab[col] + ab[KF + col]);
        else
          p = ((const float*)hprev)[(size_t)rr * KF + col];
        float hv = fmaxf(p, v);
        outb[(size_t)rr * KF + col] = f2b(hv);
        outs[(size_t)rr * KF + col] = f2b(hv * rsc[j]);
      }
    }
  } else if constexpr (EPI == 1) {
    __shared__ float smS[4][128];
    __shared__ float smQ[4][128];
    float colS[NCT], colQ[NCT];
#pragma unroll
    for (int ct = 0; ct < NCT; ++ct) { colS[ct] = 0.f; colQ[ct] = 0.f; }
#pragma unroll
    for (int ct = 0; ct < NCT; ++ct) {
      int col = ct * 16 + (lane & 15);
#pragma unroll
      for (int j = 0; j < 4; ++j) {
        int rr = rbase + j;
        if (rr >= NN) continue;
        float v = acc[ct][j];
        outb[(size_t)rr * KF + col] = f2b(v);
        colS[ct] += v;
        colQ[ct] += v * v;
      }
    }
#pragma unroll
    for (int ct = 0; ct < NCT; ++ct) {
      colS[ct] += __shfl_xor(colS[ct], 16);
      colS[ct] += __shfl_xor(colS[ct], 32);
      colQ[ct] += __shfl_xor(colQ[ct], 16);
      colQ[ct] += __shfl_xor(colQ[ct], 32);
    }
    if (lane < 16) {
#pragma unroll
      for (int ct = 0; ct < NCT; ++ct) {
        smS[w][ct * 16 + lane] = colS[ct];
        smQ[w][ct * 16 + lane] = colQ[ct];
      }
    }
    __syncthreads();
    int tid = threadIdx.x;
    if (tid < 128)
      atomicAdd(&stat[tid], smS[0][tid] + smS[1][tid] + smS[2][tid] + smS[3][tid]);
    else
      atomicAdd(&stat[tid], smQ[0][tid - 128] + smQ[1][tid - 128] + smQ[2][tid - 128] + smQ[3][tid - 128]);
  } else {
#pragma unroll
    for (int ct = 0; ct < NCT; ++ct) {
      int col = ct * 16 + (lane & 15);
#pragma unroll
      for (int j = 0; j < 4; ++j) {
        int rr = rbase + j;
        if (rr >= NN) continue;
        if (col < NCLS) outf[(size_t)rr * NCLS + col] = acc[ct][j] + bias[col];
      }
    }
  }
}

// stat (S[128], Q[128]) -> affine fold: ab[c] = gamma*rsqrt(var+eps), ab[128+c] = beta - mu*that
__global__ void k_stats_fin(const float* __restrict__ stat, const float* __restrict__ gamma,
                            const float* __restrict__ beta, float* __restrict__ ab) {
  int c = threadIdx.x;  // 128 threads
  float s = stat[c], q = stat[128 + c];
  float mu = s / (float)NN;
  float var = q / (float)NN - mu * mu;
  float rs = rsqrtf(var + EPSV);
  float a = gamma[c] * rs;
  ab[c] = a;
  ab[KF + c] = beta[c] - mu * a;
}

extern "C" void kernel_launch(void* const* d_in, const int* in_sizes, int n_in,
                              void* d_out, int out_size, void* d_ws, size_t ws_size,
                              hipStream_t stream) {
  const float* feat  = (const float*)d_in[0];
  const float* Wb    = (const float*)d_in[1];   // 3x128x128
  const float* bb2   = (const float*)d_in[2];   // 128
  const float* Wh01  = (const float*)d_in[3];   // 2x128x128
  const float* W2    = (const float*)d_in[4];   // 128x40
  const float* b2    = (const float*)d_in[5];   // 40
  const float* Wl01  = (const float*)d_in[6];   // 2x128x128
  const float* Wl2   = (const float*)d_in[7];   // 128x40
  const float* gamma = (const float*)d_in[8];   // 2x128
  const float* beta  = (const float*)d_in[9];   // 2x128
  const int* src = (const int*)d_in[10];
  const int* dst = (const int*)d_in[11];
  float* out = (float*)d_out;

  char* ws = (char*)d_ws;
  size_t off = 0;
  auto alloc = [&](size_t b) { size_t o = off; off += (b + 255) & ~(size_t)255; return o; };
  size_t z0 = alloc((size_t)(2 * NN + 2 * 256) * 4);  // deg_out|deg_in|stat (one memset)
  int* deg_out = (int*)(ws + z0);
  int* deg_in = deg_out + NN;
  float* stat = (float*)(deg_in + NN);  // 2 layers x 256 floats
  int* ptr_f = (int*)(ws + alloc((size_t)(NN + 1) * 4));
  int* ptr_r = (int*)(ws + alloc((size_t)(NN + 1) * 4));
  int* idx_f = (int*)(ws + alloc((size_t)NE * 4));
  int* idx_r = (int*)(ws + alloc((size_t)NE * 4));
  uint* rank = (uint*)(ws + alloc((size_t)NE * 4));
  float* ro = (float*)(ws + alloc((size_t)NN * 4));
  float* ri = (float*)(ws + alloc((size_t)NN * 4));
  int* bsum = (int*)(ws + alloc((size_t)2 * SCAN_NB * 4));
  ushort* featb = (ushort*)(ws + alloc((size_t)NN * KF * 2));  // also reused as t1b
  ushort* aggb  = (ushort*)(ws + alloc((size_t)NN * KF * 2));
  ushort* hmaxb = (ushort*)(ws + alloc((size_t)NN * KF * 2));  // also holds pre-norm h (bf16)
  ushort* hmaxs = (ushort*)(ws + alloc((size_t)NN * KF * 2));
  float* ab = (float*)(ws + alloc((size_t)256 * 4));
  ushort* wt = (ushort*)(ws + alloc((size_t)(WT_L2 + NCLS * KF) * 2));
  ushort* t1b = featb;  // featb dead after reverse SpMM
  (void)ws_size;

  hipMemsetAsync(ws + z0, 0, (size_t)(2 * NN + 2 * 256) * 4, stream);
  int eb = (NE + 255) / 256;
  k_deg<<<eb, 256, 0, stream>>>(src, dst, deg_out, deg_in, rank);
  k_scan_part<<<2 * SCAN_NB, 256, 0, stream>>>(deg_in, deg_out, bsum);
  k_scan_mid<<<1, 256, 0, stream>>>(bsum);
  k_scan_out<<<2 * SCAN_NB, 256, 0, stream>>>(deg_in, deg_out, bsum, ptr_f, ptr_r);
  k_rsq<<<(NN + 255) / 256, 256, 0, stream>>>(deg_out, deg_in, ro, ri);
  k_scatter<<<eb, 256, 0, stream>>>(src, dst, ptr_f, ptr_r, rank, idx_f, idx_r);
  k_convW<<<(WT_L2 + NCLS * KF + 255) / 256, 256, 0, stream>>>(Wb, Wh01, Wl01, W2, Wl2, wt);
  k_convF<<<NN * KF / 8 / 256, 256, 0, stream>>>(feat, ri, featb);

  const ushort* wtB[3] = {wt, wt + 16384, wt + 2 * 16384};
  const ushort* wtH[2] = {wt + 3 * 16384, wt + 4 * 16384};
  const ushort* wtL[2] = {wt + 5 * 16384, wt + 6 * 16384};
  const ushort* wtW2 = wt + WT_W2;
  const ushort* wtL2 = wt + WT_L2;

  int sb = (NN * 64 + 255) / 256;  // one wave per row
  // reverse conv SpMM once: aggb[u] = ro[u] * sum_{u->d} (feat*ri)[d]
  k_spmm_b<<<sb, 256, 0, stream>>>(featb, ptr_r, idx_r, ro, aggb);

  int mb = (NN + 63) / 64;
  // ---- layer 0 ----
  k_gemm<8, false, 0, false, false><<<mb, 256, 0, stream>>>(
      aggb, wtB[0], nullptr, nullptr, nullptr, feat, nullptr, ro, nullptr, hmaxb, hmaxs, nullptr);
  k_spmm_b<<<sb, 256, 0, stream>>>(hmaxs, ptr_f, idx_f, ri, t1b);
  k_gemm<8, true, 1, false, false><<<mb, 256, 0, stream>>>(
      t1b, wtH[0], hmaxb, wtL[0], nullptr, nullptr, nullptr, nullptr, nullptr, hmaxb, nullptr, stat);
  k_stats_fin<<<1, 128, 0, stream>>>(stat, gamma, beta, ab);
  // ---- layer 1 ----  (norm of h folded into hprev read via ab)
  k_gemm<8, false, 0, false, true><<<mb, 256, 0, stream>>>(
      aggb, wtB[1], nullptr, nullptr, nullptr, hmaxb, ab, ro, nullptr, hmaxb, hmaxs, nullptr);
  k_spmm_b<<<sb, 256, 0, stream>>>(hmaxs, ptr_f, idx_f, ri, t1b);
  k_gemm<8, true, 1, false, false><<<mb, 256, 0, stream>>>(
      t1b, wtH[1], hmaxb, wtL[1], nullptr, nullptr, nullptr, nullptr, nullptr, hmaxb, nullptr, stat + 256);
  k_stats_fin<<<1, 128, 0, stream>>>(stat + 256, gamma + KF, beta + KF, ab);
  // ---- layer 2 ----
  k_gemm<8, false, 0, true, true><<<mb, 256, 0, stream>>>(
      aggb, wtB[2], nullptr, nullptr, bb2, hmaxb, ab, ro, nullptr, hmaxb, hmaxs, nullptr);
  k_spmm_b<<<sb, 256, 0, stream>>>(hmaxs, ptr_f, idx_f, ri, t1b);
  k_gemm<3, true, 2, false, false><<<mb, 256, 0, stream>>>(
      t1b, wtW2, hmaxb, wtL2, b2, nullptr, nullptr, nullptr, out, nullptr, nullptr, nullptr);
}

// Round 8
// 821.675 us; speedup vs baseline: 2.5814x; 1.0774x over previous
//
#include <hip/hip_runtime.h>

#define NN 100000
#define NE 1600000
#define KF 128
#define NCLS 40
#define EPSV 1e-5f
#define NBUK 391            // node buckets of 256 (391*256 = 100096 >= NN)
#define TBUK 782            // fwd + rev
#define EPB 4096            // edges per P1 block
#define P1B ((NE + EPB - 1) / EPB)  // 391
#define CAP 6144            // kb_build LDS stage capacity (avg 4096, +32 sigma)

typedef short bf16x8 __attribute__((ext_vector_type(8)));
typedef float f32x4 __attribute__((ext_vector_type(4)));
typedef unsigned short ushort;
typedef unsigned int uint;
typedef ushort ush8 __attribute__((ext_vector_type(8)));

static __device__ __forceinline__ int imax1(int x) { return x > 0 ? x : 1; }

static __device__ __forceinline__ ushort f2b(float f) {  // fp32 -> bf16 RNE
  uint u = __builtin_bit_cast(uint, f);
  u += 0x7fffu + ((u >> 16) & 1u);
  return (ushort)(u >> 16);
}
static __device__ __forceinline__ float b2f(uint bits16) {
  return __builtin_bit_cast(float, bits16 << 16);
}

// ================= bucketed graph build (no global atomics on hot path) =================
// bucket of node n: n>>8. fwd key=dst (builds idx_f/ptr_f/deg_in), rev key=src.

__global__ __launch_bounds__(256) void kb_hist(const int* __restrict__ src, const int* __restrict__ dst,
                                               int* __restrict__ gcount) {
  __shared__ int hist[TBUK];
  for (int t = threadIdx.x; t < TBUK; t += 256) hist[t] = 0;
  __syncthreads();
  int base = blockIdx.x * EPB + threadIdx.x;
#pragma unroll
  for (int i = 0; i < 16; ++i) {
    int e = base + i * 256;
    if (e < NE) {
      atomicAdd(&hist[dst[e] >> 8], 1);
      atomicAdd(&hist[NBUK + (src[e] >> 8)], 1);
    }
  }
  __syncthreads();
  for (int t = threadIdx.x; t < TBUK; t += 256)
    if (hist[t]) atomicAdd(&gcount[t], hist[t]);
}

__global__ __launch_bounds__(1024) void kb_scan(const int* __restrict__ gcount,
                                                int* __restrict__ gbase, int* __restrict__ gcur) {
  __shared__ int sm[1024];
  int t = threadIdx.x;
  int v = (t < TBUK) ? gcount[t] : 0;
  sm[t] = v;
  __syncthreads();
  for (int d = 1; d < 1024; d <<= 1) {
    int x = (t >= d) ? sm[t - d] : 0;
    __syncthreads();
    sm[t] += x;
    __syncthreads();
  }
  int excl = sm[t] - v;
  if (t <= TBUK) gbase[t] = excl;   // gbase[TBUK] = 2*NE
  if (t < TBUK) gcur[t] = excl;
}

__global__ __launch_bounds__(256) void kb_place(const int* __restrict__ src, const int* __restrict__ dst,
                                                int* __restrict__ gcur,
                                                uint2* __restrict__ pairs_f, uint2* __restrict__ pairs_r) {
  __shared__ uint2 stage[EPB];
  __shared__ int hist[TBUK];
  __shared__ int sbase[TBUK];
  for (int t = threadIdx.x; t < TBUK; t += 256) hist[t] = 0;
  __syncthreads();
  int base = blockIdx.x * EPB;
  int nloc = min(EPB, NE - base);
  for (int i = threadIdx.x; i < nloc; i += 256) {
    int e = base + i;
    uint2 p;
    p.x = (uint)src[e];
    p.y = (uint)dst[e];
    stage[i] = p;
    atomicAdd(&hist[p.y >> 8], 1);
    atomicAdd(&hist[NBUK + (p.x >> 8)], 1);
  }
  __syncthreads();
  for (int t = threadIdx.x; t < TBUK; t += 256)
    sbase[t] = hist[t] ? atomicAdd(&gcur[t], hist[t]) : 0;
  __syncthreads();
  for (int i = threadIdx.x; i < nloc; i += 256) {
    uint2 p = stage[i];
    int pf = atomicAdd(&sbase[p.y >> 8], 1);
    int pr = atomicAdd(&sbase[NBUK + (p.x >> 8)], 1);
    pairs_f[pf] = make_uint2(p.y, p.x);       // key=dst, val=src
    pairs_r[pr - NE] = make_uint2(p.x, p.y);  // key=src, val=dst
  }
}

__global__ __launch_bounds__(256) void kb_build(const uint2* __restrict__ pairs_f,
                                                const uint2* __restrict__ pairs_r,
                                                const int* __restrict__ gbase,
                                                int* __restrict__ idx_f, int* __restrict__ idx_r,
                                                int* __restrict__ ptr_f, int* __restrict__ ptr_r,
                                                int* __restrict__ deg_in, int* __restrict__ deg_out) {
  __shared__ uint2 stage[CAP];
  __shared__ int deg[256];
  __shared__ int ss[256];
  __shared__ int cur[256];
  int b = blockIdx.x;
  int rev = (int)(b >= NBUK);
  int k = b - rev * NBUK;
  const uint2* pairs = rev ? pairs_r : pairs_f;
  int* idx = rev ? idx_r : idx_f;
  int* ptr = rev ? ptr_r : ptr_f;
  int* degA = rev ? deg_out : deg_in;
  int gb = gbase[b];
  int cnt = gbase[b + 1] - gb;
  int base = gb - rev * NE;
  int lo = k << 8;
  int t = threadIdx.x;
  deg[t] = 0;
  __syncthreads();
  for (int i = t; i < cnt; i += 256) {   // load + count
    uint2 p = pairs[base + i];
    if (i < CAP) stage[i] = p;
    atomicAdd(&deg[(int)p.x - lo], 1);
  }
  __syncthreads();
  int dv = deg[t];
  if (lo + t < NN) degA[lo + t] = dv;
  ss[t] = dv;
  __syncthreads();
  for (int d = 1; d < 256; d <<= 1) {    // exclusive scan
    int x = (t >= d) ? ss[t - d] : 0;
    __syncthreads();
    ss[t] += x;
    __syncthreads();
  }
  int ex = ss[t] - dv;
  if (lo + t < NN) ptr[lo + t] = base + ex;
  cur[t] = ex;
  if (b == NBUK - 1 && t == 0) ptr_f[NN] = NE;
  if (b == TBUK - 1 && t == 0) ptr_r[NN] = NE;
  __syncthreads();
  for (int i = t; i < cnt; i += 256) {   // place (L2-local 16KB window)
    uint2 p = (i < CAP) ? stage[i] : pairs[base + i];
    int pos = atomicAdd(&cur[(int)p.x - lo], 1);
    idx[base + pos] = (int)p.y;
  }
}

__global__ void k_rsq(const int* __restrict__ deg_out, const int* __restrict__ deg_in,
                      float* __restrict__ ro, float* __restrict__ ri) {
  int i = blockIdx.x * blockDim.x + threadIdx.x;
  if (i < NN) {
    ro[i] = rsqrtf((float)imax1(deg_out[i]));
    ri[i] = rsqrtf((float)imax1(deg_in[i]));
  }
}

// ---------------- fp32 -> bf16 convert, row-scaled by ri (rev-SpMM pre-scale) ----------------
__global__ __launch_bounds__(256) void k_convF(const float* __restrict__ in, const float* __restrict__ ri,
                       ushort* __restrict__ out) {
  int t = blockIdx.x * blockDim.x + threadIdx.x;
  int i = t * 8;  // grid sized exactly; 16 threads per row
  float w = ri[t >> 4];
  float4 a = *(const float4*)(in + i);
  float4 b = *(const float4*)(in + i + 4);
  ush8 o;
  o[0] = f2b(a.x * w); o[1] = f2b(a.y * w); o[2] = f2b(a.z * w); o[3] = f2b(a.w * w);
  o[4] = f2b(b.x * w); o[5] = f2b(b.y * w); o[6] = f2b(b.z * w); o[7] = f2b(b.w * w);
  *(ush8*)(out + i) = o;
}

// ---------------- weight convert+transpose: wt[n][k] = bf16(W[k][n]) ----------------
// layout: [0..3)x16384 Wb | [3..5)x16384 Wh01 | [5..7)x16384 Wl01 | 40x128 W2 | 40x128 Wl2
#define WT_W2 (7 * 16384)
#define WT_L2 (WT_W2 + NCLS * KF)
__global__ __launch_bounds__(256) void k_convW(const float* __restrict__ Wb, const float* __restrict__ Wh01,
                       const float* __restrict__ Wl01, const float* __restrict__ W2,
                       const float* __restrict__ Wl2, ushort* __restrict__ wt) {
  int i = blockIdx.x * blockDim.x + threadIdx.x;  // grid sized exactly (124928)
  float v;
  if (i < WT_W2) {
    int m = i >> 14, r = (i >> 7) & 127, k = i & 127;
    const float* srcm = (m < 3) ? (Wb + m * 16384)
                      : (m < 5) ? (Wh01 + (m - 3) * 16384)
                                : (Wl01 + (m - 5) * 16384);
    v = srcm[k * KF + r];
  } else {
    int j = i - WT_W2;
    int m2 = j / (NCLS * KF);
    int t = j - m2 * (NCLS * KF);
    int n = t >> 7, k = t & 127;
    v = (m2 ? Wl2 : W2)[k * NCLS + n];
  }
  wt[i] = f2b(v);
}

// ---------------- SpMM (pre-scaled rows): out[v] = wout[v] * sum_{u in row v} in[u] ----------------
// one wave per row; 4 edge streams per wave (16 lanes x uint4 = 256B per edge);
// unroll 2 => 8 edges in flight; final cross-stream combine via 2 shfl_xor steps
__global__ __launch_bounds__(256) void k_spmm_b(const ushort* __restrict__ in,
                      const int* __restrict__ ptr, const int* __restrict__ idx,
                      const float* __restrict__ wout, ushort* __restrict__ out) {
  int wid = (blockIdx.x * blockDim.x + threadIdx.x) >> 6;
  int lane = threadIdx.x & 63;
  if (wid >= NN) return;
  int beg = ptr[wid], end = ptr[wid + 1];
  int strm = lane >> 4;          // edge stream 0..3
  int c8 = (lane & 15) * 8;      // 8 bf16 columns per lane
  float s[8];
#pragma unroll
  for (int j = 0; j < 8; ++j) s[j] = 0.f;
  int p = beg + strm;
  for (; p + 4 < end; p += 8) {  // edges p and p+4 both valid
    int u0 = idx[p], u1 = idx[p + 4];
    uint4 v0 = *(const uint4*)(in + (size_t)u0 * KF + c8);
    uint4 v1 = *(const uint4*)(in + (size_t)u1 * KF + c8);
    s[0] += b2f(v0.x & 0xffffu) + b2f(v1.x & 0xffffu);
    s[1] += b2f(v0.x >> 16)     + b2f(v1.x >> 16);
    s[2] += b2f(v0.y & 0xffffu) + b2f(v1.y & 0xffffu);
    s[3] += b2f(v0.y >> 16)     + b2f(v1.y >> 16);
    s[4] += b2f(v0.z & 0xffffu) + b2f(v1.z & 0xffffu);
    s[5] += b2f(v0.z >> 16)     + b2f(v1.z >> 16);
    s[6] += b2f(v0.w & 0xffffu) + b2f(v1.w & 0xffffu);
    s[7] += b2f(v0.w >> 16)     + b2f(v1.w >> 16);
  }
  if (p < end) {
    int u0 = idx[p];
    uint4 v0 = *(const uint4*)(in + (size_t)u0 * KF + c8);
    s[0] += b2f(v0.x & 0xffffu);
    s[1] += b2f(v0.x >> 16);
    s[2] += b2f(v0.y & 0xffffu);
    s[3] += b2f(v0.y >> 16);
    s[4] += b2f(v0.z & 0xffffu);
    s[5] += b2f(v0.z >> 16);
    s[6] += b2f(v0.w & 0xffffu);
    s[7] += b2f(v0.w >> 16);
  }
#pragma unroll
  for (int j = 0; j < 8; ++j) {
    s[j] += __shfl_xor(s[j], 16);
    s[j] += __shfl_xor(s[j], 32);
  }
  if (lane < 16) {
    float w = wout[wid];
    ush8 o;
#pragma unroll
    for (int j = 0; j < 8; ++j) o[j] = f2b(s[j] * w);
    *(ush8*)(out + (size_t)wid * KF + c8) = o;
  }
}

// ---------------- MFMA GEMM, no LDS (LDS only for EPI1 stats): wave holds A-frags in regs ----------------
// block = 4 waves, 64 rows; wave w -> rows blk*64 + w*16, all NCT*16 cols.
// EPI 0: outb = bf16(max(prev, acc(+bias)));  outs = bf16(same * ro[row]);
//        prev = NORMP ? relu(bf16(h)*a+b) : fp32 h
// EPI 1: outb = bf16(acc) (pre-norm h) + fused column stats (sum, sumsq) -> atomicAdd(stat)
// EPI 2: outf fp32 (N=NCLS) = acc + bias     (final layer)
template <int NCT, bool DUAL, int EPI, bool HASB, bool NORMP>
__global__ __launch_bounds__(256) void k_gemm(
    const ushort* __restrict__ A1, const ushort* __restrict__ Wt1,
    const ushort* __restrict__ A2, const ushort* __restrict__ Wt2,
    const float* __restrict__ bias, const void* __restrict__ hprev,
    const float* __restrict__ ab, const float* __restrict__ rosc,
    float* __restrict__ outf, ushort* __restrict__ outb, ushort* __restrict__ outs,
    float* __restrict__ stat) {
  int lane = threadIdx.x & 63;
  int w = threadIdx.x >> 6;
  int r0 = blockIdx.x * 64 + w * 16;
  int arow = r0 + (lane & 15);
  if (arow > NN - 1) arow = NN - 1;
  int k0 = (lane >> 4) * 8;

  bf16x8 a1[4], a2[4];
#pragma unroll
  for (int ks = 0; ks < 4; ++ks) {
    a1[ks] = *(const bf16x8*)(A1 + (size_t)arow * KF + ks * 32 + k0);
    if (DUAL) a2[ks] = *(const bf16x8*)(A2 + (size_t)arow * KF + ks * 32 + k0);
  }
  f32x4 acc[NCT];
#pragma unroll
  for (int ct = 0; ct < NCT; ++ct) acc[ct] = (f32x4){0.f, 0.f, 0.f, 0.f};

#pragma unroll
  for (int ks = 0; ks < 4; ++ks) {
#pragma unroll
    for (int ct = 0; ct < NCT; ++ct) {
      int ncol = ct * 16 + (lane & 15);
      if (EPI == 2 && ncol > NCLS - 1) ncol = NCLS - 1;
      bf16x8 b1 = *(const bf16x8*)(Wt1 + (size_t)ncol * KF + ks * 32 + k0);
      acc[ct] = __builtin_amdgcn_mfma_f32_16x16x32_bf16(a1[ks], b1, acc[ct], 0, 0, 0);
      if (DUAL) {
        bf16x8 b2 = *(const bf16x8*)(Wt2 + (size_t)ncol * KF + ks * 32 + k0);
        acc[ct] = __builtin_amdgcn_mfma_f32_16x16x32_bf16(a2[ks], b2, acc[ct], 0, 0, 0);
      }
    }
  }

  int rbase = r0 + (lane >> 4) * 4;
  if constexpr (EPI == 0) {
    float rsc[4];
#pragma unroll
    for (int j = 0; j < 4; ++j) rsc[j] = rosc[min(rbase + j, NN - 1)];
#pragma unroll
    for (int ct = 0; ct < NCT; ++ct) {
      int col = ct * 16 + (lane & 15);
#pragma unroll
      for (int j = 0; j < 4; ++j) {
        int rr = rbase + j;
        if (rr >= NN) continue;
        float v = acc[ct][j];
        if (HASB) v += bias[col];
        float p;
        if (NORMP)
          p = fmaxf(0.f, b2f((uint)((const ushort*)hprev)[(size_t)rr * KF + col]) * ab[col] + ab[KF + col]);
        else
          p = ((const float*)hprev)[(size_t)rr * KF + col];
        float hv = fmaxf(p, v);
        outb[(size_t)rr * KF + col] = f2b(hv);
        outs[(size_t)rr * KF + col] = f2b(hv * rsc[j]);
      }
    }
  } else if constexpr (EPI == 1) {
    __shared__ float smS[4][128];
    __shared__ float smQ[4][128];
    float colS[NCT], colQ[NCT];
#pragma unroll
    for (int ct = 0; ct < NCT; ++ct) { colS[ct] = 0.f; colQ[ct] = 0.f; }
#pragma unroll
    for (int ct = 0; ct < NCT; ++ct) {
      int col = ct * 16 + (lane & 15);
#pragma unroll
      for (int j = 0; j < 4; ++j) {
        int rr = rbase + j;
        if (rr >= NN) continue;
        float v = acc[ct][j];
        outb[(size_t)rr * KF + col] = f2b(v);
        colS[ct] += v;
        colQ[ct] += v * v;
      }
    }
#pragma unroll
    for (int ct = 0; ct < NCT; ++ct) {
      colS[ct] += __shfl_xor(colS[ct], 16);
      colS[ct] += __shfl_xor(colS[ct], 32);
      colQ[ct] += __shfl_xor(colQ[ct], 16);
      colQ[ct] += __shfl_xor(colQ[ct], 32);
    }
    if (lane < 16) {
#pragma unroll
      for (int ct = 0; ct < NCT; ++ct) {
        smS[w][ct * 16 + lane] = colS[ct];
        smQ[w][ct * 16 + lane] = colQ[ct];
      }
    }
    __syncthreads();
    int tid = threadIdx.x;
    if (tid < 128)
      atomicAdd(&stat[tid], smS[0][tid] + smS[1][tid] + smS[2][tid] + smS[3][tid]);
    else
      atomicAdd(&stat[tid], smQ[0][tid - 128] + smQ[1][tid - 128] + smQ[2][tid - 128] + smQ[3][tid - 128]);
  } else {
#pragma unroll
    for (int ct = 0; ct < NCT; ++ct) {
      int col = ct * 16 + (lane & 15);
#pragma unroll
      for (int j = 0; j < 4; ++j) {
        int rr = rbase + j;
        if (rr >= NN) continue;
        if (col < NCLS) outf[(size_t)rr * NCLS + col] = acc[ct][j] + bias[col];
      }
    }
  }
}

// stat (S[128], Q[128]) -> affine fold: ab[c] = gamma*rsqrt(var+eps), ab[128+c] = beta - mu*that
__global__ void k_stats_fin(const float* __restrict__ stat, const float* __restrict__ gamma,
                            const float* __restrict__ beta, float* __restrict__ ab) {
  int c = threadIdx.x;  // 128 threads
  float s = stat[c], q = stat[128 + c];
  float mu = s / (float)NN;
  float var = q / (float)NN - mu * mu;
  float rs = rsqrtf(var + EPSV);
  float a = gamma[c] * rs;
  ab[c] = a;
  ab[KF + c] = beta[c] - mu * a;
}

extern "C" void kernel_launch(void* const* d_in, const int* in_sizes, int n_in,
                              void* d_out, int out_size, void* d_ws, size_t ws_size,
                              hipStream_t stream) {
  const float* feat  = (const float*)d_in[0];
  const float* Wb    = (const float*)d_in[1];   // 3x128x128
  const float* bb2   = (const float*)d_in[2];   // 128
  const float* Wh01  = (const float*)d_in[3];   // 2x128x128
  const float* W2    = (const float*)d_in[4];   // 128x40
  const float* b2    = (const float*)d_in[5];   // 40
  const float* Wl01  = (const float*)d_in[6];   // 2x128x128
  const float* Wl2   = (const float*)d_in[7];   // 128x40
  const float* gamma = (const float*)d_in[8];   // 2x128
  const float* beta  = (const float*)d_in[9];   // 2x128
  const int* src = (const int*)d_in[10];
  const int* dst = (const int*)d_in[11];
  float* out = (float*)d_out;

  char* ws = (char*)d_ws;
  size_t off = 0;
  auto alloc = [&](size_t b) { size_t o = off; off += (b + 255) & ~(size_t)255; return o; };
  size_t z0 = alloc((size_t)(TBUK + 512) * 4);  // gcount | stat (one memset)
  int* gcount = (int*)(ws + z0);
  float* stat = (float*)(gcount + TBUK);        // 2 layers x 256 floats
  int* gbase = (int*)(ws + alloc((size_t)(TBUK + 1) * 4));
  int* gcur  = (int*)(ws + alloc((size_t)TBUK * 4));
  int* deg_out = (int*)(ws + alloc((size_t)NN * 4));
  int* deg_in  = (int*)(ws + alloc((size_t)NN * 4));
  int* ptr_f = (int*)(ws + alloc((size_t)(NN + 1) * 4));
  int* ptr_r = (int*)(ws + alloc((size_t)(NN + 1) * 4));
  int* idx_f = (int*)(ws + alloc((size_t)NE * 4));
  int* idx_r = (int*)(ws + alloc((size_t)NE * 4));
  uint2* pairs_f = (uint2*)(ws + alloc((size_t)NE * 8));
  uint2* pairs_r = (uint2*)(ws + alloc((size_t)NE * 8));
  float* ro = (float*)(ws + alloc((size_t)NN * 4));
  float* ri = (float*)(ws + alloc((size_t)NN * 4));
  ushort* featb = (ushort*)(ws + alloc((size_t)NN * KF * 2));  // also reused as t1b
  ushort* aggb  = (ushort*)(ws + alloc((size_t)NN * KF * 2));
  ushort* hmaxb = (ushort*)(ws + alloc((size_t)NN * KF * 2));  // also holds pre-norm h (bf16)
  ushort* hmaxs = (ushort*)(ws + alloc((size_t)NN * KF * 2));
  float* ab = (float*)(ws + alloc((size_t)256 * 4));
  ushort* wt = (ushort*)(ws + alloc((size_t)(WT_L2 + NCLS * KF) * 2));
  ushort* t1b = featb;  // featb dead after reverse SpMM
  (void)ws_size;

  hipMemsetAsync(ws + z0, 0, (size_t)(TBUK + 512) * 4, stream);
  kb_hist<<<P1B, 256, 0, stream>>>(src, dst, gcount);
  kb_scan<<<1, 1024, 0, stream>>>(gcount, gbase, gcur);
  kb_place<<<P1B, 256, 0, stream>>>(src, dst, gcur, pairs_f, pairs_r);
  kb_build<<<TBUK, 256, 0, stream>>>(pairs_f, pairs_r, gbase, idx_f, idx_r,
                                     ptr_f, ptr_r, deg_in, deg_out);
  k_rsq<<<(NN + 255) / 256, 256, 0, stream>>>(deg_out, deg_in, ro, ri);
  k_convW<<<(WT_L2 + NCLS * KF + 255) / 256, 256, 0, stream>>>(Wb, Wh01, Wl01, W2, Wl2, wt);
  k_convF<<<NN * KF / 8 / 256, 256, 0, stream>>>(feat, ri, featb);

  const ushort* wtB[3] = {wt, wt + 16384, wt + 2 * 16384};
  const ushort* wtH[2] = {wt + 3 * 16384, wt + 4 * 16384};
  const ushort* wtL[2] = {wt + 5 * 16384, wt + 6 * 16384};
  const ushort* wtW2 = wt + WT_W2;
  const ushort* wtL2 = wt + WT_L2;

  int sb = (NN * 64 + 255) / 256;  // one wave per row
  // reverse conv SpMM once: aggb[u] = ro[u] * sum_{u->d} (feat*ri)[d]
  k_spmm_b<<<sb, 256, 0, stream>>>(featb, ptr_r, idx_r, ro, aggb);

  int mb = (NN + 63) / 64;
  // ---- layer 0 ----
  k_gemm<8, false, 0, false, false><<<mb, 256, 0, stream>>>(
      aggb, wtB[0], nullptr, nullptr, nullptr, feat, nullptr, ro, nullptr, hmaxb, hmaxs, nullptr);
  k_spmm_b<<<sb, 256, 0, stream>>>(hmaxs, ptr_f, idx_f, ri, t1b);
  k_gemm<8, true, 1, false, false><<<mb, 256, 0, stream>>>(
      t1b, wtH[0], hmaxb, wtL[0], nullptr, nullptr, nullptr, nullptr, nullptr, hmaxb, nullptr, stat);
  k_stats_fin<<<1, 128, 0, stream>>>(stat, gamma, beta, ab);
  // ---- layer 1 ----  (norm of h folded into hprev read via ab)
  k_gemm<8, false, 0, false, true><<<mb, 256, 0, stream>>>(
      aggb, wtB[1], nullptr, nullptr, nullptr, hmaxb, ab, ro, nullptr, hmaxb, hmaxs, nullptr);
  k_spmm_b<<<sb, 256, 0, stream>>>(hmaxs, ptr_f, idx_f, ri, t1b);
  k_gemm<8, true, 1, false, false><<<mb, 256, 0, stream>>>(
      t1b, wtH[1], hmaxb, wtL[1], nullptr, nullptr, nullptr, nullptr, nullptr, hmaxb, nullptr, stat + 256);
  k_stats_fin<<<1, 128, 0, stream>>>(stat + 256, gamma + KF, beta + KF, ab);
  // ---- layer 2 ----
  k_gemm<8, false, 0, true, true><<<mb, 256, 0, stream>>>(
      aggb, wtB[2], nullptr, nullptr, bb2, hmaxb, ab, ro, nullptr, hmaxb, hmaxs, nullptr);
  k_spmm_b<<<sb, 256, 0, stream>>>(hmaxs, ptr_f, idx_f, ri, t1b);
  k_gemm<3, true, 2, false, false><<<mb, 256, 0, stream>>>(
      t1b, wtW2, hmaxb, wtL2, b2, nullptr, nullptr, nullptr, out, nullptr, nullptr, nullptr);
}

// Round 9
// 784.648 us; speedup vs baseline: 2.7033x; 1.0472x over previous
//
#include <hip/hip_runtime.h>

#define NN 100000
#define NE 1600000
#define KF 128
#define NCLS 40
#define EPSV 1e-5f
#define NBUK 391            // node buckets of 256 (391*256 = 100096 >= NN)
#define TBUK 782            // fwd + rev
#define EPB 4096            // edges per P1 block
#define P1B ((NE + EPB - 1) / EPB)  // 391
#define CAP 6144            // kb_build LDS stage capacity (avg 4096, +32 sigma)

typedef short bf16x8 __attribute__((ext_vector_type(8)));
typedef float f32x4 __attribute__((ext_vector_type(4)));
typedef unsigned short ushort;
typedef unsigned int uint;
typedef ushort ush8 __attribute__((ext_vector_type(8)));

static __device__ __forceinline__ int imax1(int x) { return x > 0 ? x : 1; }

static __device__ __forceinline__ ushort f2b(float f) {  // fp32 -> bf16 RNE
  uint u = __builtin_bit_cast(uint, f);
  u += 0x7fffu + ((u >> 16) & 1u);
  return (ushort)(u >> 16);
}
static __device__ __forceinline__ float b2f(uint bits16) {
  return __builtin_bit_cast(float, bits16 << 16);
}

// ================= bucketed graph build (no global atomics on hot path) =================
// bucket of node n: n>>8. fwd key=dst (builds idx_f/ptr_f/deg_in), rev key=src.

__global__ __launch_bounds__(256) void kb_hist(const int* __restrict__ src, const int* __restrict__ dst,
                                               int* __restrict__ gcount) {
  __shared__ int hist[TBUK];
  for (int t = threadIdx.x; t < TBUK; t += 256) hist[t] = 0;
  __syncthreads();
  int base = blockIdx.x * EPB + threadIdx.x;
#pragma unroll
  for (int i = 0; i < 16; ++i) {
    int e = base + i * 256;
    if (e < NE) {
      atomicAdd(&hist[dst[e] >> 8], 1);
      atomicAdd(&hist[NBUK + (src[e] >> 8)], 1);
    }
  }
  __syncthreads();
  for (int t = threadIdx.x; t < TBUK; t += 256)
    if (hist[t]) atomicAdd(&gcount[t], hist[t]);
}

__global__ __launch_bounds__(1024) void kb_scan(const int* __restrict__ gcount,
                                                int* __restrict__ gbase, int* __restrict__ gcur) {
  __shared__ int sm[1024];
  int t = threadIdx.x;
  int v = (t < TBUK) ? gcount[t] : 0;
  sm[t] = v;
  __syncthreads();
  for (int d = 1; d < 1024; d <<= 1) {
    int x = (t >= d) ? sm[t - d] : 0;
    __syncthreads();
    sm[t] += x;
    __syncthreads();
  }
  int excl = sm[t] - v;
  if (t <= TBUK) gbase[t] = excl;   // gbase[TBUK] = 2*NE
  if (t < TBUK) gcur[t] = excl;
}

__global__ __launch_bounds__(256) void kb_place(const int* __restrict__ src, const int* __restrict__ dst,
                                                int* __restrict__ gcur,
                                                uint2* __restrict__ pairs_f, uint2* __restrict__ pairs_r) {
  __shared__ uint2 stage[EPB];
  __shared__ int hist[TBUK];
  __shared__ int sbase[TBUK];
  for (int t = threadIdx.x; t < TBUK; t += 256) hist[t] = 0;
  __syncthreads();
  int base = blockIdx.x * EPB;
  int nloc = min(EPB, NE - base);
  for (int i = threadIdx.x; i < nloc; i += 256) {
    int e = base + i;
    uint2 p;
    p.x = (uint)src[e];
    p.y = (uint)dst[e];
    stage[i] = p;
    atomicAdd(&hist[p.y >> 8], 1);
    atomicAdd(&hist[NBUK + (p.x >> 8)], 1);
  }
  __syncthreads();
  for (int t = threadIdx.x; t < TBUK; t += 256)
    sbase[t] = hist[t] ? atomicAdd(&gcur[t], hist[t]) : 0;
  __syncthreads();
  for (int i = threadIdx.x; i < nloc; i += 256) {
    uint2 p = stage[i];
    int pf = atomicAdd(&sbase[p.y >> 8], 1);
    int pr = atomicAdd(&sbase[NBUK + (p.x >> 8)], 1);
    pairs_f[pf] = make_uint2(p.y, p.x);       // key=dst, val=src
    pairs_r[pr - NE] = make_uint2(p.x, p.y);  // key=src, val=dst
  }
}

__global__ __launch_bounds__(256) void kb_build(const uint2* __restrict__ pairs_f,
                                                const uint2* __restrict__ pairs_r,
                                                const int* __restrict__ gbase,
                                                int* __restrict__ idx_f, int* __restrict__ idx_r,
                                                int* __restrict__ ptr_f, int* __restrict__ ptr_r,
                                                int* __restrict__ deg_in, int* __restrict__ deg_out) {
  __shared__ uint2 stage[CAP];
  __shared__ int deg[256];
  __shared__ int ss[256];
  __shared__ int cur[256];
  int b = blockIdx.x;
  int rev = (int)(b >= NBUK);
  int k = b - rev * NBUK;
  const uint2* pairs = rev ? pairs_r : pairs_f;
  int* idx = rev ? idx_r : idx_f;
  int* ptr = rev ? ptr_r : ptr_f;
  int* degA = rev ? deg_out : deg_in;
  int gb = gbase[b];
  int cnt = gbase[b + 1] - gb;
  int base = gb - rev * NE;
  int lo = k << 8;
  int t = threadIdx.x;
  deg[t] = 0;
  __syncthreads();
  for (int i = t; i < cnt; i += 256) {   // load + count
    uint2 p = pairs[base + i];
    if (i < CAP) stage[i] = p;
    atomicAdd(&deg[(int)p.x - lo], 1);
  }
  __syncthreads();
  int dv = deg[t];
  if (lo + t < NN) degA[lo + t] = dv;
  ss[t] = dv;
  __syncthreads();
  for (int d = 1; d < 256; d <<= 1) {    // exclusive scan
    int x = (t >= d) ? ss[t - d] : 0;
    __syncthreads();
    ss[t] += x;
    __syncthreads();
  }
  int ex = ss[t] - dv;
  if (lo + t < NN) ptr[lo + t] = base + ex;
  cur[t] = ex;
  if (b == NBUK - 1 && t == 0) ptr_f[NN] = NE;
  if (b == TBUK - 1 && t == 0) ptr_r[NN] = NE;
  __syncthreads();
  for (int i = t; i < cnt; i += 256) {   // place (L2-local 16KB window)
    uint2 p = (i < CAP) ? stage[i] : pairs[base + i];
    int pos = atomicAdd(&cur[(int)p.x - lo], 1);
    idx[base + pos] = (int)p.y;
  }
}

__global__ void k_rsq(const int* __restrict__ deg_out, const int* __restrict__ deg_in,
                      float* __restrict__ ro, float* __restrict__ ri) {
  int i = blockIdx.x * blockDim.x + threadIdx.x;
  if (i < NN) {
    ro[i] = rsqrtf((float)imax1(deg_out[i]));
    ri[i] = rsqrtf((float)imax1(deg_in[i]));
  }
}

// ---------------- fp32 -> bf16 convert, row-scaled by ri (rev-SpMM pre-scale) ----------------
__global__ __launch_bounds__(256) void k_convF(const float* __restrict__ in, const float* __restrict__ ri,
                       ushort* __restrict__ out) {
  int t = blockIdx.x * blockDim.x + threadIdx.x;
  int i = t * 8;  // grid sized exactly; 16 threads per row
  float w = ri[t >> 4];
  float4 a = *(const float4*)(in + i);
  float4 b = *(const float4*)(in + i + 4);
  ush8 o;
  o[0] = f2b(a.x * w); o[1] = f2b(a.y * w); o[2] = f2b(a.z * w); o[3] = f2b(a.w * w);
  o[4] = f2b(b.x * w); o[5] = f2b(b.y * w); o[6] = f2b(b.z * w); o[7] = f2b(b.w * w);
  *(ush8*)(out + i) = o;
}

// ---------------- weight convert+transpose: wt[n][k] = bf16(W[k][n]) ----------------
// layout: [0..3)x16384 Wb | [3..5)x16384 Wh01 | [5..7)x16384 Wl01 | 40x128 W2 | 40x128 Wl2
#define WT_W2 (7 * 16384)
#define WT_L2 (WT_W2 + NCLS * KF)
__global__ __launch_bounds__(256) void k_convW(const float* __restrict__ Wb, const float* __restrict__ Wh01,
                       const float* __restrict__ Wl01, const float* __restrict__ W2,
                       const float* __restrict__ Wl2, ushort* __restrict__ wt) {
  int i = blockIdx.x * blockDim.x + threadIdx.x;  // grid sized exactly (124928)
  float v;
  if (i < WT_W2) {
    int m = i >> 14, r = (i >> 7) & 127, k = i & 127;
    const float* srcm = (m < 3) ? (Wb + m * 16384)
                      : (m < 5) ? (Wh01 + (m - 3) * 16384)
                                : (Wl01 + (m - 5) * 16384);
    v = srcm[k * KF + r];
  } else {
    int j = i - WT_W2;
    int m2 = j / (NCLS * KF);
    int t = j - m2 * (NCLS * KF);
    int n = t >> 7, k = t & 127;
    v = (m2 ? Wl2 : W2)[k * NCLS + n];
  }
  wt[i] = f2b(v);
}

// ---------------- SpMM (pre-scaled rows): out[v] = wout[v] * sum_{u in row v} in[u] ----------------
// one wave per row; 4 edge streams per wave (16 lanes x uint4 = 256B per edge);
// unroll 2 => 8 edges in flight; final cross-stream combine via 2 shfl_xor steps
__global__ __launch_bounds__(256) void k_spmm_b(const ushort* __restrict__ in,
                      const int* __restrict__ ptr, const int* __restrict__ idx,
                      const float* __restrict__ wout, ushort* __restrict__ out) {
  int wid = (blockIdx.x * blockDim.x + threadIdx.x) >> 6;
  int lane = threadIdx.x & 63;
  if (wid >= NN) return;
  int beg = ptr[wid], end = ptr[wid + 1];
  int strm = lane >> 4;          // edge stream 0..3
  int c8 = (lane & 15) * 8;      // 8 bf16 columns per lane
  float s[8];
#pragma unroll
  for (int j = 0; j < 8; ++j) s[j] = 0.f;
  int p = beg + strm;
  for (; p + 4 < end; p += 8) {  // edges p and p+4 both valid
    int u0 = idx[p], u1 = idx[p + 4];
    uint4 v0 = *(const uint4*)(in + (size_t)u0 * KF + c8);
    uint4 v1 = *(const uint4*)(in + (size_t)u1 * KF + c8);
    s[0] += b2f(v0.x & 0xffffu) + b2f(v1.x & 0xffffu);
    s[1] += b2f(v0.x >> 16)     + b2f(v1.x >> 16);
    s[2] += b2f(v0.y & 0xffffu) + b2f(v1.y & 0xffffu);
    s[3] += b2f(v0.y >> 16)     + b2f(v1.y >> 16);
    s[4] += b2f(v0.z & 0xffffu) + b2f(v1.z & 0xffffu);
    s[5] += b2f(v0.z >> 16)     + b2f(v1.z >> 16);
    s[6] += b2f(v0.w & 0xffffu) + b2f(v1.w & 0xffffu);
    s[7] += b2f(v0.w >> 16)     + b2f(v1.w >> 16);
  }
  if (p < end) {
    int u0 = idx[p];
    uint4 v0 = *(const uint4*)(in + (size_t)u0 * KF + c8);
    s[0] += b2f(v0.x & 0xffffu);
    s[1] += b2f(v0.x >> 16);
    s[2] += b2f(v0.y & 0xffffu);
    s[3] += b2f(v0.y >> 16);
    s[4] += b2f(v0.z & 0xffffu);
    s[5] += b2f(v0.z >> 16);
    s[6] += b2f(v0.w & 0xffffu);
    s[7] += b2f(v0.w >> 16);
  }
#pragma unroll
  for (int j = 0; j < 8; ++j) {
    s[j] += __shfl_xor(s[j], 16);
    s[j] += __shfl_xor(s[j], 32);
  }
  if (lane < 16) {
    float w = wout[wid];
    ush8 o;
#pragma unroll
    for (int j = 0; j < 8; ++j) o[j] = f2b(s[j] * w);
    *(ush8*)(out + (size_t)wid * KF + c8) = o;
  }
}

// ---------------- MFMA GEMM, no LDS (LDS only for EPI1 stats): wave holds A-frags in regs ----------------
// block = 4 waves, 64 rows; wave w -> rows blk*64 + w*16, all NCT*16 cols.
// Latency fix (r8): per-ks batched B-frag loads (8-16 indep loads in flight, 4 waits
// instead of 64) + epilogue operands (hprev/rosc) prefetched before the MFMA loop.
// EPI 0: outb = bf16(max(prev, acc(+bias)));  outs = bf16(same * ro[row]);
//        prev = NORMP ? relu(bf16(h)*a+b) : fp32 h
// EPI 1: outb = bf16(acc) (pre-norm h) + fused column stats (sum, sumsq) -> atomicAdd(stat)
// EPI 2: outf fp32 (N=NCLS) = acc + bias     (final layer)
template <int NCT, bool DUAL, int EPI, bool HASB, bool NORMP>
__global__ __launch_bounds__(256) void k_gemm(
    const ushort* __restrict__ A1, const ushort* __restrict__ Wt1,
    const ushort* __restrict__ A2, const ushort* __restrict__ Wt2,
    const float* __restrict__ bias, const void* __restrict__ hprev,
    const float* __restrict__ ab, const float* __restrict__ rosc,
    float* __restrict__ outf, ushort* __restrict__ outb, ushort* __restrict__ outs,
    float* __restrict__ stat) {
  int lane = threadIdx.x & 63;
  int w = threadIdx.x >> 6;
  int r0 = blockIdx.x * 64 + w * 16;
  int arow = r0 + (lane & 15);
  if (arow > NN - 1) arow = NN - 1;
  int k0 = (lane >> 4) * 8;
  int rbase = r0 + (lane >> 4) * 4;

  bf16x8 a1[4], a2[4];
#pragma unroll
  for (int ks = 0; ks < 4; ++ks) {
    a1[ks] = *(const bf16x8*)(A1 + (size_t)arow * KF + ks * 32 + k0);
    if (DUAL) a2[ks] = *(const bf16x8*)(A2 + (size_t)arow * KF + ks * 32 + k0);
  }

  // epilogue-operand prefetch (issues before/during MFMA phase)
  float rsc[4];
  float hp[EPI == 0 ? NCT : 1][EPI == 0 ? 4 : 1];
  if constexpr (EPI == 0) {
#pragma unroll
    for (int j = 0; j < 4; ++j) rsc[j] = rosc[min(rbase + j, NN - 1)];
#pragma unroll
    for (int ct = 0; ct < NCT; ++ct) {
      int col = ct * 16 + (lane & 15);
#pragma unroll
      for (int j = 0; j < 4; ++j) {
        int rr = min(rbase + j, NN - 1);
        if (NORMP)
          hp[ct][j] = b2f((uint)((const ushort*)hprev)[(size_t)rr * KF + col]);
        else
          hp[ct][j] = ((const float*)hprev)[(size_t)rr * KF + col];
      }
    }
  }

  f32x4 acc[NCT];
#pragma unroll
  for (int ct = 0; ct < NCT; ++ct) acc[ct] = (f32x4){0.f, 0.f, 0.f, 0.f};

#pragma unroll
  for (int ks = 0; ks < 4; ++ks) {
    bf16x8 b1[NCT], b2[DUAL ? NCT : 1];
#pragma unroll
    for (int ct = 0; ct < NCT; ++ct) {
      int ncol = ct * 16 + (lane & 15);
      if (EPI == 2 && ncol > NCLS - 1) ncol = NCLS - 1;
      b1[ct] = *(const bf16x8*)(Wt1 + (size_t)ncol * KF + ks * 32 + k0);
      if (DUAL) b2[ct] = *(const bf16x8*)(Wt2 + (size_t)ncol * KF + ks * 32 + k0);
    }
#pragma unroll
    for (int ct = 0; ct < NCT; ++ct) {
      acc[ct] = __builtin_amdgcn_mfma_f32_16x16x32_bf16(a1[ks], b1[ct], acc[ct], 0, 0, 0);
      if (DUAL) acc[ct] = __builtin_amdgcn_mfma_f32_16x16x32_bf16(a2[ks], b2[ct], acc[ct], 0, 0, 0);
    }
  }

  if constexpr (EPI == 0) {
#pragma unroll
    for (int ct = 0; ct < NCT; ++ct) {
      int col = ct * 16 + (lane & 15);
#pragma unroll
      for (int j = 0; j < 4; ++j) {
        int rr = rbase + j;
        if (rr >= NN) continue;
        float v = acc[ct][j];
        if (HASB) v += bias[col];
        float p = hp[ct][j];
        if (NORMP) p = fmaxf(0.f, p * ab[col] + ab[KF + col]);
        float hv = fmaxf(p, v);
        outb[(size_t)rr * KF + col] = f2b(hv);
        outs[(size_t)rr * KF + col] = f2b(hv * rsc[j]);
      }
    }
  } else if constexpr (EPI == 1) {
    __shared__ float smS[4][128];
    __shared__ float smQ[4][128];
    float colS[NCT], colQ[NCT];
#pragma unroll
    for (int ct = 0; ct < NCT; ++ct) { colS[ct] = 0.f; colQ[ct] = 0.f; }
#pragma unroll
    for (int ct = 0; ct < NCT; ++ct) {
      int col = ct * 16 + (lane & 15);
#pragma unroll
      for (int j = 0; j < 4; ++j) {
        int rr = rbase + j;
        if (rr >= NN) continue;
        float v = acc[ct][j];
        outb[(size_t)rr * KF + col] = f2b(v);
        colS[ct] += v;
        colQ[ct] += v * v;
      }
    }
#pragma unroll
    for (int ct = 0; ct < NCT; ++ct) {
      colS[ct] += __shfl_xor(colS[ct], 16);
      colS[ct] += __shfl_xor(colS[ct], 32);
      colQ[ct] += __shfl_xor(colQ[ct], 16);
      colQ[ct] += __shfl_xor(colQ[ct], 32);
    }
    if (lane < 16) {
#pragma unroll
      for (int ct = 0; ct < NCT; ++ct) {
        smS[w][ct * 16 + lane] = colS[ct];
        smQ[w][ct * 16 + lane] = colQ[ct];
      }
    }
    __syncthreads();
    int tid = threadIdx.x;
    if (tid < 128)
      atomicAdd(&stat[tid], smS[0][tid] + smS[1][tid] + smS[2][tid] + smS[3][tid]);
    else
      atomicAdd(&stat[tid], smQ[0][tid - 128] + smQ[1][tid - 128] + smQ[2][tid - 128] + smQ[3][tid - 128]);
  } else {
#pragma unroll
    for (int ct = 0; ct < NCT; ++ct) {
      int col = ct * 16 + (lane & 15);
#pragma unroll
      for (int j = 0; j < 4; ++j) {
        int rr = rbase + j;
        if (rr >= NN) continue;
        if (col < NCLS) outf[(size_t)rr * NCLS + col] = acc[ct][j] + bias[col];
      }
    }
  }
}

// stat (S[128], Q[128]) -> affine fold: ab[c] = gamma*rsqrt(var+eps), ab[128+c] = beta - mu*that
__global__ void k_stats_fin(const float* __restrict__ stat, const float* __restrict__ gamma,
                            const float* __restrict__ beta, float* __restrict__ ab) {
  int c = threadIdx.x;  // 128 threads
  float s = stat[c], q = stat[128 + c];
  float mu = s / (float)NN;
  float var = q / (float)NN - mu * mu;
  float rs = rsqrtf(var + EPSV);
  float a = gamma[c] * rs;
  ab[c] = a;
  ab[KF + c] = beta[c] - mu * a;
}

extern "C" void kernel_launch(void* const* d_in, const int* in_sizes, int n_in,
                              void* d_out, int out_size, void* d_ws, size_t ws_size,
                              hipStream_t stream) {
  const float* feat  = (const float*)d_in[0];
  const float* Wb    = (const float*)d_in[1];   // 3x128x128
  const float* bb2   = (const float*)d_in[2];   // 128
  const float* Wh01  = (const float*)d_in[3];   // 2x128x128
  const float* W2    = (const float*)d_in[4];   // 128x40
  const float* b2    = (const float*)d_in[5];   // 40
  const float* Wl01  = (const float*)d_in[6];   // 2x128x128
  const float* Wl2   = (const float*)d_in[7];   // 128x40
  const float* gamma = (const float*)d_in[8];   // 2x128
  const float* beta  = (const float*)d_in[9];   // 2x128
  const int* src = (const int*)d_in[10];
  const int* dst = (const int*)d_in[11];
  float* out = (float*)d_out;

  char* ws = (char*)d_ws;
  size_t off = 0;
  auto alloc = [&](size_t b) { size_t o = off; off += (b + 255) & ~(size_t)255; return o; };
  size_t z0 = alloc((size_t)(TBUK + 512) * 4);  // gcount | stat (one memset)
  int* gcount = (int*)(ws + z0);
  float* stat = (float*)(gcount + TBUK);        // 2 layers x 256 floats
  int* gbase = (int*)(ws + alloc((size_t)(TBUK + 1) * 4));
  int* gcur  = (int*)(ws + alloc((size_t)TBUK * 4));
  int* deg_out = (int*)(ws + alloc((size_t)NN * 4));
  int* deg_in  = (int*)(ws + alloc((size_t)NN * 4));
  int* ptr_f = (int*)(ws + alloc((size_t)(NN + 1) * 4));
  int* ptr_r = (int*)(ws + alloc((size_t)(NN + 1) * 4));
  int* idx_f = (int*)(ws + alloc((size_t)NE * 4));
  int* idx_r = (int*)(ws + alloc((size_t)NE * 4));
  uint2* pairs_f = (uint2*)(ws + alloc((size_t)NE * 8));
  uint2* pairs_r = (uint2*)(ws + alloc((size_t)NE * 8));
  float* ro = (float*)(ws + alloc((size_t)NN * 4));
  float* ri = (float*)(ws + alloc((size_t)NN * 4));
  ushort* featb = (ushort*)(ws + alloc((size_t)NN * KF * 2));  // also reused as t1b
  ushort* aggb  = (ushort*)(ws + alloc((size_t)NN * KF * 2));
  ushort* hmaxb = (ushort*)(ws + alloc((size_t)NN * KF * 2));  // also holds pre-norm h (bf16)
  ushort* hmaxs = (ushort*)(ws + alloc((size_t)NN * KF * 2));
  float* ab = (float*)(ws + alloc((size_t)256 * 4));
  ushort* wt = (ushort*)(ws + alloc((size_t)(WT_L2 + NCLS * KF) * 2));
  ushort* t1b = featb;  // featb dead after reverse SpMM
  (void)ws_size;

  hipMemsetAsync(ws + z0, 0, (size_t)(TBUK + 512) * 4, stream);
  kb_hist<<<P1B, 256, 0, stream>>>(src, dst, gcount);
  kb_scan<<<1, 1024, 0, stream>>>(gcount, gbase, gcur);
  kb_place<<<P1B, 256, 0, stream>>>(src, dst, gcur, pairs_f, pairs_r);
  kb_build<<<TBUK, 256, 0, stream>>>(pairs_f, pairs_r, gbase, idx_f, idx_r,
                                     ptr_f, ptr_r, deg_in, deg_out);
  k_rsq<<<(NN + 255) / 256, 256, 0, stream>>>(deg_out, deg_in, ro, ri);
  k_convW<<<(WT_L2 + NCLS * KF + 255) / 256, 256, 0, stream>>>(Wb, Wh01, Wl01, W2, Wl2, wt);
  k_convF<<<NN * KF / 8 / 256, 256, 0, stream>>>(feat, ri, featb);

  const ushort* wtB[3] = {wt, wt + 16384, wt + 2 * 16384};
  const ushort* wtH[2] = {wt + 3 * 16384, wt + 4 * 16384};
  const ushort* wtL[2] = {wt + 5 * 16384, wt + 6 * 16384};
  const ushort* wtW2 = wt + WT_W2;
  const ushort* wtL2 = wt + WT_L2;

  int sb = (NN * 64 + 255) / 256;  // one wave per row
  // reverse conv SpMM once: aggb[u] = ro[u] * sum_{u->d} (feat*ri)[d]
  k_spmm_b<<<sb, 256, 0, stream>>>(featb, ptr_r, idx_r, ro, aggb);

  int mb = (NN + 63) / 64;
  // ---- layer 0 ----
  k_gemm<8, false, 0, false, false><<<mb, 256, 0, stream>>>(
      aggb, wtB[0], nullptr, nullptr, nullptr, feat, nullptr, ro, nullptr, hmaxb, hmaxs, nullptr);
  k_spmm_b<<<sb, 256, 0, stream>>>(hmaxs, ptr_f, idx_f, ri, t1b);
  k_gemm<8, true, 1, false, false><<<mb, 256, 0, stream>>>(
      t1b, wtH[0], hmaxb, wtL[0], nullptr, nullptr, nullptr, nullptr, nullptr, hmaxb, nullptr, stat);
  k_stats_fin<<<1, 128, 0, stream>>>(stat, gamma, beta, ab);
  // ---- layer 1 ----  (norm of h folded into hprev read via ab)
  k_gemm<8, false, 0, false, true><<<mb, 256, 0, stream>>>(
      aggb, wtB[1], nullptr, nullptr, nullptr, hmaxb, ab, ro, nullptr, hmaxb, hmaxs, nullptr);
  k_spmm_b<<<sb, 256, 0, stream>>>(hmaxs, ptr_f, idx_f, ri, t1b);
  k_gemm<8, true, 1, false, false><<<mb, 256, 0, stream>>>(
      t1b, wtH[1], hmaxb, wtL[1], nullptr, nullptr, nullptr, nullptr, nullptr, hmaxb, nullptr, stat + 256);
  k_stats_fin<<<1, 128, 0, stream>>>(stat + 256, gamma + KF, beta + KF, ab);
  // ---- layer 2 ----
  k_gemm<8, false, 0, true, true><<<mb, 256, 0, stream>>>(
      aggb, wtB[2], nullptr, nullptr, bb2, hmaxb, ab, ro, nullptr, hmaxb, hmaxs, nullptr);
  k_spmm_b<<<sb, 256, 0, stream>>>(hmaxs, ptr_f, idx_f, ri, t1b);
  k_gemm<3, true, 2, false, false><<<mb, 256, 0, stream>>>(
      t1b, wtW2, hmaxb, wtL2, b2, nullptr, nullptr, nullptr, out, nullptr, nullptr, nullptr);
}

// Round 11
// 755.012 us; speedup vs baseline: 2.8094x; 1.0393x over previous
//
#include <hip/hip_runtime.h>

#define NN 100000
#define NE 1600000
#define KF 128
#define NCLS 40
#define EPSV 1e-5f
#define NBUK 391            // node buckets of 256 (391*256 = 100096 >= NN)
#define TBUK 782            // fwd + rev
#define EPB 4096            // edges per P1 block
#define P1B ((NE + EPB - 1) / EPB)  // 391
#define CAP 6144            // kb_build LDS stage capacity (avg 4096, +32 sigma)

typedef short bf16x8 __attribute__((ext_vector_type(8)));
typedef float f32x4 __attribute__((ext_vector_type(4)));
typedef unsigned short ushort;
typedef unsigned int uint;
typedef ushort ush8 __attribute__((ext_vector_type(8)));

static __device__ __forceinline__ int imax1(int x) { return x > 0 ? x : 1; }

static __device__ __forceinline__ ushort f2b(float f) {  // fp32 -> bf16 RNE
  uint u = __builtin_bit_cast(uint, f);
  u += 0x7fffu + ((u >> 16) & 1u);
  return (ushort)(u >> 16);
}
static __device__ __forceinline__ float b2f(uint bits16) {
  return __builtin_bit_cast(float, bits16 << 16);
}

// ================= bucketed graph build (no global atomics on hot path) =================
// bucket of node n: n>>8. fwd key=dst (builds idx_f/ptr_f/deg_in), rev key=src.

__global__ __launch_bounds__(256) void kb_hist(const int* __restrict__ src, const int* __restrict__ dst,
                                               int* __restrict__ gcount) {
  __shared__ int hist[TBUK];
  for (int t = threadIdx.x; t < TBUK; t += 256) hist[t] = 0;
  __syncthreads();
  int base = blockIdx.x * EPB + threadIdx.x;
#pragma unroll
  for (int i = 0; i < 16; ++i) {
    int e = base + i * 256;
    if (e < NE) {
      atomicAdd(&hist[dst[e] >> 8], 1);
      atomicAdd(&hist[NBUK + (src[e] >> 8)], 1);
    }
  }
  __syncthreads();
  for (int t = threadIdx.x; t < TBUK; t += 256)
    if (hist[t]) atomicAdd(&gcount[t], hist[t]);
}

__global__ __launch_bounds__(1024) void kb_scan(const int* __restrict__ gcount,
                                                int* __restrict__ gbase, int* __restrict__ gcur) {
  __shared__ int sm[1024];
  int t = threadIdx.x;
  int v = (t < TBUK) ? gcount[t] : 0;
  sm[t] = v;
  __syncthreads();
  for (int d = 1; d < 1024; d <<= 1) {
    int x = (t >= d) ? sm[t - d] : 0;
    __syncthreads();
    sm[t] += x;
    __syncthreads();
  }
  int excl = sm[t] - v;
  if (t <= TBUK) gbase[t] = excl;   // gbase[TBUK] = 2*NE
  if (t < TBUK) gcur[t] = excl;
}

__global__ __launch_bounds__(256) void kb_place(const int* __restrict__ src, const int* __restrict__ dst,
                                                int* __restrict__ gcur,
                                                uint2* __restrict__ pairs_f, uint2* __restrict__ pairs_r) {
  __shared__ uint2 stage[EPB];
  __shared__ int hist[TBUK];
  __shared__ int sbase[TBUK];
  for (int t = threadIdx.x; t < TBUK; t += 256) hist[t] = 0;
  __syncthreads();
  int base = blockIdx.x * EPB;
  int nloc = min(EPB, NE - base);
  for (int i = threadIdx.x; i < nloc; i += 256) {
    int e = base + i;
    uint2 p;
    p.x = (uint)src[e];
    p.y = (uint)dst[e];
    stage[i] = p;
    atomicAdd(&hist[p.y >> 8], 1);
    atomicAdd(&hist[NBUK + (p.x >> 8)], 1);
  }
  __syncthreads();
  for (int t = threadIdx.x; t < TBUK; t += 256)
    sbase[t] = hist[t] ? atomicAdd(&gcur[t], hist[t]) : 0;
  __syncthreads();
  for (int i = threadIdx.x; i < nloc; i += 256) {
    uint2 p = stage[i];
    int pf = atomicAdd(&sbase[p.y >> 8], 1);
    int pr = atomicAdd(&sbase[NBUK + (p.x >> 8)], 1);
    pairs_f[pf] = make_uint2(p.y, p.x);       // key=dst, val=src
    pairs_r[pr - NE] = make_uint2(p.x, p.y);  // key=src, val=dst
  }
}

__global__ __launch_bounds__(256) void kb_build(const uint2* __restrict__ pairs_f,
                                                const uint2* __restrict__ pairs_r,
                                                const int* __restrict__ gbase,
                                                int* __restrict__ idx_f, int* __restrict__ idx_r,
                                                int* __restrict__ ptr_f, int* __restrict__ ptr_r,
                                                int* __restrict__ deg_in, int* __restrict__ deg_out) {
  __shared__ uint2 stage[CAP];
  __shared__ int deg[256];
  __shared__ int ss[256];
  __shared__ int cur[256];
  int b = blockIdx.x;
  int rev = (int)(b >= NBUK);
  int k = b - rev * NBUK;
  const uint2* pairs = rev ? pairs_r : pairs_f;
  int* idx = rev ? idx_r : idx_f;
  int* ptr = rev ? ptr_r : ptr_f;
  int* degA = rev ? deg_out : deg_in;
  int gb = gbase[b];
  int cnt = gbase[b + 1] - gb;
  int base = gb - rev * NE;
  int lo = k << 8;
  int t = threadIdx.x;
  deg[t] = 0;
  __syncthreads();
  for (int i = t; i < cnt; i += 256) {   // load + count
    uint2 p = pairs[base + i];
    if (i < CAP) stage[i] = p;
    atomicAdd(&deg[(int)p.x - lo], 1);
  }
  __syncthreads();
  int dv = deg[t];
  if (lo + t < NN) degA[lo + t] = dv;
  ss[t] = dv;
  __syncthreads();
  for (int d = 1; d < 256; d <<= 1) {    // exclusive scan
    int x = (t >= d) ? ss[t - d] : 0;
    __syncthreads();
    ss[t] += x;
    __syncthreads();
  }
  int ex = ss[t] - dv;
  if (lo + t < NN) ptr[lo + t] = base + ex;
  cur[t] = ex;
  if (b == NBUK - 1 && t == 0) ptr_f[NN] = NE;
  if (b == TBUK - 1 && t == 0) ptr_r[NN] = NE;
  __syncthreads();
  for (int i = t; i < cnt; i += 256) {   // place (L2-local 16KB window)
    uint2 p = (i < CAP) ? stage[i] : pairs[base + i];
    int pos = atomicAdd(&cur[(int)p.x - lo], 1);
    idx[base + pos] = (int)p.y;
  }
}

__global__ void k_rsq(const int* __restrict__ deg_out, const int* __restrict__ deg_in,
                      float* __restrict__ ro, float* __restrict__ ri) {
  int i = blockIdx.x * blockDim.x + threadIdx.x;
  if (i < NN) {
    ro[i] = rsqrtf((float)imax1(deg_out[i]));
    ri[i] = rsqrtf((float)imax1(deg_in[i]));
  }
}

// ---------------- fp32 -> bf16 convert, row-scaled by ri (rev-SpMM pre-scale) ----------------
__global__ __launch_bounds__(256) void k_convF(const float* __restrict__ in, const float* __restrict__ ri,
                       ushort* __restrict__ out) {
  int t = blockIdx.x * blockDim.x + threadIdx.x;
  int i = t * 8;  // grid sized exactly; 16 threads per row
  float w = ri[t >> 4];
  float4 a = *(const float4*)(in + i);
  float4 b = *(const float4*)(in + i + 4);
  ush8 o;
  o[0] = f2b(a.x * w); o[1] = f2b(a.y * w); o[2] = f2b(a.z * w); o[3] = f2b(a.w * w);
  o[4] = f2b(b.x * w); o[5] = f2b(b.y * w); o[6] = f2b(b.z * w); o[7] = f2b(b.w * w);
  *(ush8*)(out + i) = o;
}

// ---------------- weight convert+transpose: wt[n][k] = bf16(W[k][n]) ----------------
// layout: [0..3)x16384 Wb | [3..5)x16384 Wh01 | [5..7)x16384 Wl01 | 40x128 W2 | 40x128 Wl2
#define WT_W2 (7 * 16384)
#define WT_L2 (WT_W2 + NCLS * KF)
__global__ __launch_bounds__(256) void k_convW(const float* __restrict__ Wb, const float* __restrict__ Wh01,
                       const float* __restrict__ Wl01, const float* __restrict__ W2,
                       const float* __restrict__ Wl2, ushort* __restrict__ wt) {
  int i = blockIdx.x * blockDim.x + threadIdx.x;  // grid sized exactly (124928)
  float v;
  if (i < WT_W2) {
    int m = i >> 14, r = (i >> 7) & 127, k = i & 127;
    const float* srcm = (m < 3) ? (Wb + m * 16384)
                      : (m < 5) ? (Wh01 + (m - 3) * 16384)
                                : (Wl01 + (m - 5) * 16384);
    v = srcm[k * KF + r];
  } else {
    int j = i - WT_W2;
    int m2 = j / (NCLS * KF);
    int t = j - m2 * (NCLS * KF);
    int n = t >> 7, k = t & 127;
    v = (m2 ? Wl2 : W2)[k * NCLS + n];
  }
  wt[i] = f2b(v);
}

// ---------------- SpMM (pre-scaled rows): out[v] = wout[v] * sum_{u in row v} in[u] ----------------
// one wave per row; 4 edge streams per wave (16 lanes x uint4 = 256B per edge);
// unroll 2 => 8 edges in flight; final cross-stream combine via 2 shfl_xor steps
__global__ __launch_bounds__(256) void k_spmm_b(const ushort* __restrict__ in,
                      const int* __restrict__ ptr, const int* __restrict__ idx,
                      const float* __restrict__ wout, ushort* __restrict__ out) {
  int wid = (blockIdx.x * blockDim.x + threadIdx.x) >> 6;
  int lane = threadIdx.x & 63;
  if (wid >= NN) return;
  int beg = ptr[wid], end = ptr[wid + 1];
  int strm = lane >> 4;          // edge stream 0..3
  int c8 = (lane & 15) * 8;      // 8 bf16 columns per lane
  float s[8];
#pragma unroll
  for (int j = 0; j < 8; ++j) s[j] = 0.f;
  int p = beg + strm;
  for (; p + 4 < end; p += 8) {  // edges p and p+4 both valid
    int u0 = idx[p], u1 = idx[p + 4];
    uint4 v0 = *(const uint4*)(in + (size_t)u0 * KF + c8);
    uint4 v1 = *(const uint4*)(in + (size_t)u1 * KF + c8);
    s[0] += b2f(v0.x & 0xffffu) + b2f(v1.x & 0xffffu);
    s[1] += b2f(v0.x >> 16)     + b2f(v1.x >> 16);
    s[2] += b2f(v0.y & 0xffffu) + b2f(v1.y & 0xffffu);
    s[3] += b2f(v0.y >> 16)     + b2f(v1.y >> 16);
    s[4] += b2f(v0.z & 0xffffu) + b2f(v1.z & 0xffffu);
    s[5] += b2f(v0.z >> 16)     + b2f(v1.z >> 16);
    s[6] += b2f(v0.w & 0xffffu) + b2f(v1.w & 0xffffu);
    s[7] += b2f(v0.w >> 16)     + b2f(v1.w >> 16);
  }
  if (p < end) {
    int u0 = idx[p];
    uint4 v0 = *(const uint4*)(in + (size_t)u0 * KF + c8);
    s[0] += b2f(v0.x & 0xffffu);
    s[1] += b2f(v0.x >> 16);
    s[2] += b2f(v0.y & 0xffffu);
    s[3] += b2f(v0.y >> 16);
    s[4] += b2f(v0.z & 0xffffu);
    s[5] += b2f(v0.z >> 16);
    s[6] += b2f(v0.w & 0xffffu);
    s[7] += b2f(v0.w >> 16);
  }
#pragma unroll
  for (int j = 0; j < 8; ++j) {
    s[j] += __shfl_xor(s[j], 16);
    s[j] += __shfl_xor(s[j], 32);
  }
  if (lane < 16) {
    float w = wout[wid];
    ush8 o;
#pragma unroll
    for (int j = 0; j < 8; ++j) o[j] = f2b(s[j] * w);
    *(ush8*)(out + (size_t)wid * KF + c8) = o;
  }
}

// ---------------- MFMA GEMM, register-resident B ----------------
// block = 4 waves, 64 rows x 128 cols. Wave w owns cols [w*32, w*32+32) (WCT=2 col-tiles)
// for ALL 64 rows (4 row-tiles). B-frags loop-invariant -> loaded ONCE into regs.
// r10 fix: EPI1 must NOT write in-place over its A2 input (cross-wave race: waves
// share rows but split cols) -> EPI1 writes to a dedicated hpreb buffer.
// EPI 0: outb = bf16(max(prev, acc(+bias)));  outs = bf16(same * ro[row]);
//        prev = NORMP ? relu(bf16 hprev*a+b) : fp32 hprev   (col-partitioned: race-free)
// EPI 1: outb = bf16(acc) + fused column stats (each col owned by exactly one wave)
// EPI 2: outf fp32 (N=NCLS) = acc + bias  (cols >= NCLS predicated off)
template <int WCT, bool DUAL, int EPI, bool HASB, bool NORMP>
__global__ __launch_bounds__(256) void k_gemm(
    const ushort* __restrict__ A1, const ushort* __restrict__ Wt1,
    const ushort* __restrict__ A2, const ushort* __restrict__ Wt2,
    const float* __restrict__ bias, const void* __restrict__ hprev,
    const float* __restrict__ ab, const float* __restrict__ rosc,
    float* __restrict__ outf, ushort* __restrict__ outb, ushort* __restrict__ outs,
    float* __restrict__ stat) {
  int lane = threadIdx.x & 63;
  int w = threadIdx.x >> 6;
  int r0 = blockIdx.x * 64;
  int wcol = w * (WCT * 16);
  int k0 = (lane >> 4) * 8;
  int l15 = lane & 15;
  int g = lane >> 4;

  // loop-invariant B fragments (held in VGPRs for the whole kernel)
  bf16x8 b1[WCT][4];
  bf16x8 b2[DUAL ? WCT : 1][DUAL ? 4 : 1];
#pragma unroll
  for (int ct = 0; ct < WCT; ++ct) {
    int ncol = wcol + ct * 16 + l15;
    if (EPI == 2) ncol = min(ncol, NCLS - 1);
#pragma unroll
    for (int ks = 0; ks < 4; ++ks) {
      b1[ct][ks] = *(const bf16x8*)(Wt1 + (size_t)ncol * KF + ks * 32 + k0);
      if (DUAL) b2[ct][ks] = *(const bf16x8*)(Wt2 + (size_t)ncol * KF + ks * 32 + k0);
    }
  }

  f32x4 acc[4][WCT];
#pragma unroll
  for (int rt = 0; rt < 4; ++rt)
#pragma unroll
    for (int ct = 0; ct < WCT; ++ct) acc[rt][ct] = (f32x4){0.f, 0.f, 0.f, 0.f};

#pragma unroll
  for (int rt = 0; rt < 4; ++rt) {
    int arow = min(r0 + rt * 16 + l15, NN - 1);
    bf16x8 a1[4], a2[DUAL ? 4 : 1];
#pragma unroll
    for (int ks = 0; ks < 4; ++ks) {
      a1[ks] = *(const bf16x8*)(A1 + (size_t)arow * KF + ks * 32 + k0);
      if (DUAL) a2[ks] = *(const bf16x8*)(A2 + (size_t)arow * KF + ks * 32 + k0);
    }
#pragma unroll
    for (int ks = 0; ks < 4; ++ks)
#pragma unroll
      for (int ct = 0; ct < WCT; ++ct) {
        acc[rt][ct] = __builtin_amdgcn_mfma_f32_16x16x32_bf16(a1[ks], b1[ct][ks], acc[rt][ct], 0, 0, 0);
        if (DUAL)
          acc[rt][ct] = __builtin_amdgcn_mfma_f32_16x16x32_bf16(a2[ks], b2[ct][ks], acc[rt][ct], 0, 0, 0);
      }
  }

  if constexpr (EPI == 0) {
#pragma unroll
    for (int rt = 0; rt < 4; ++rt) {
      int rbase = r0 + rt * 16 + g * 4;
#pragma unroll
      for (int j = 0; j < 4; ++j) {
        int rr = rbase + j;
        if (rr >= NN) continue;
        float rs = rosc[rr];
#pragma unroll
        for (int ct = 0; ct < WCT; ++ct) {
          int col = wcol + ct * 16 + l15;
          float v = acc[rt][ct][j];
          if (HASB) v += bias[col];
          float p;
          if (NORMP)
            p = fmaxf(0.f, b2f((uint)((const ushort*)hprev)[(size_t)rr * KF + col]) * ab[col] + ab[KF + col]);
          else
            p = ((const float*)hprev)[(size_t)rr * KF + col];
          float hv = fmaxf(p, v);
          outb[(size_t)rr * KF + col] = f2b(hv);
          outs[(size_t)rr * KF + col] = f2b(hv * rs);
        }
      }
    }
  } else if constexpr (EPI == 1) {
    __shared__ float smS[128];
    __shared__ float smQ[128];
    float colS[WCT], colQ[WCT];
#pragma unroll
    for (int ct = 0; ct < WCT; ++ct) { colS[ct] = 0.f; colQ[ct] = 0.f; }
#pragma unroll
    for (int rt = 0; rt < 4; ++rt) {
      int rbase = r0 + rt * 16 + g * 4;
#pragma unroll
      for (int ct = 0; ct < WCT; ++ct) {
        int col = wcol + ct * 16 + l15;
#pragma unroll
        for (int j = 0; j < 4; ++j) {
          int rr = rbase + j;
          if (rr >= NN) continue;
          float v = acc[rt][ct][j];
          outb[(size_t)rr * KF + col] = f2b(v);
          colS[ct] += v;
          colQ[ct] += v * v;
        }
      }
    }
#pragma unroll
    for (int ct = 0; ct < WCT; ++ct) {   // sum across the 4 row-groups of the wave
      colS[ct] += __shfl_xor(colS[ct], 16);
      colS[ct] += __shfl_xor(colS[ct], 32);
      colQ[ct] += __shfl_xor(colQ[ct], 16);
      colQ[ct] += __shfl_xor(colQ[ct], 32);
    }
    if (lane < 16) {   // each column owned by exactly one wave -> no cross-wave merge
#pragma unroll
      for (int ct = 0; ct < WCT; ++ct) {
        smS[wcol + ct * 16 + lane] = colS[ct];
        smQ[wcol + ct * 16 + lane] = colQ[ct];
      }
    }
    __syncthreads();
    int tid = threadIdx.x;
    if (tid < 128)
      atomicAdd(&stat[tid], smS[tid]);
    else
      atomicAdd(&stat[tid], smQ[tid - 128]);
  } else {
#pragma unroll
    for (int rt = 0; rt < 4; ++rt) {
      int rbase = r0 + rt * 16 + g * 4;
#pragma unroll
      for (int ct = 0; ct < WCT; ++ct) {
        int col = wcol + ct * 16 + l15;
        if (col >= NCLS) continue;
#pragma unroll
        for (int j = 0; j < 4; ++j) {
          int rr = rbase + j;
          if (rr >= NN) continue;
          outf[(size_t)rr * NCLS + col] = acc[rt][ct][j] + bias[col];
        }
      }
    }
  }
}

// stat (S[128], Q[128]) -> affine fold: ab[c] = gamma*rsqrt(var+eps), ab[128+c] = beta - mu*that
__global__ void k_stats_fin(const float* __restrict__ stat, const float* __restrict__ gamma,
                            const float* __restrict__ beta, float* __restrict__ ab) {
  int c = threadIdx.x;  // 128 threads
  float s = stat[c], q = stat[128 + c];
  float mu = s / (float)NN;
  float var = q / (float)NN - mu * mu;
  float rs = rsqrtf(var + EPSV);
  float a = gamma[c] * rs;
  ab[c] = a;
  ab[KF + c] = beta[c] - mu * a;
}

extern "C" void kernel_launch(void* const* d_in, const int* in_sizes, int n_in,
                              void* d_out, int out_size, void* d_ws, size_t ws_size,
                              hipStream_t stream) {
  const float* feat  = (const float*)d_in[0];
  const float* Wb    = (const float*)d_in[1];   // 3x128x128
  const float* bb2   = (const float*)d_in[2];   // 128
  const float* Wh01  = (const float*)d_in[3];   // 2x128x128
  const float* W2    = (const float*)d_in[4];   // 128x40
  const float* b2    = (const float*)d_in[5];   // 40
  const float* Wl01  = (const float*)d_in[6];   // 2x128x128
  const float* Wl2   = (const float*)d_in[7];   // 128x40
  const float* gamma = (const float*)d_in[8];   // 2x128
  const float* beta  = (const float*)d_in[9];   // 2x128
  const int* src = (const int*)d_in[10];
  const int* dst = (const int*)d_in[11];
  float* out = (float*)d_out;

  char* ws = (char*)d_ws;
  size_t off = 0;
  auto alloc = [&](size_t b) { size_t o = off; off += (b + 255) & ~(size_t)255; return o; };
  size_t z0 = alloc((size_t)(TBUK + 512) * 4);  // gcount | stat (one memset)
  int* gcount = (int*)(ws + z0);
  float* stat = (float*)(gcount + TBUK);        // 2 layers x 256 floats
  int* gbase = (int*)(ws + alloc((size_t)(TBUK + 1) * 4));
  int* gcur  = (int*)(ws + alloc((size_t)TBUK * 4));
  int* deg_out = (int*)(ws + alloc((size_t)NN * 4));
  int* deg_in  = (int*)(ws + alloc((size_t)NN * 4));
  int* ptr_f = (int*)(ws + alloc((size_t)(NN + 1) * 4));
  int* ptr_r = (int*)(ws + alloc((size_t)(NN + 1) * 4));
  int* idx_f = (int*)(ws + alloc((size_t)NE * 4));
  int* idx_r = (int*)(ws + alloc((size_t)NE * 4));
  uint2* pairs_f = (uint2*)(ws + alloc((size_t)NE * 8));
  uint2* pairs_r = (uint2*)(ws + alloc((size_t)NE * 8));
  float* ro = (float*)(ws + alloc((size_t)NN * 4));
  float* ri = (float*)(ws + alloc((size_t)NN * 4));
  ushort* featb = (ushort*)(ws + alloc((size_t)NN * KF * 2));  // also reused as t1b
  ushort* aggb  = (ushort*)(ws + alloc((size_t)NN * KF * 2));
  ushort* hmaxb = (ushort*)(ws + alloc((size_t)NN * KF * 2));
  ushort* hmaxs = (ushort*)(ws + alloc((size_t)NN * KF * 2));
  ushort* hpreb = (ushort*)(ws + alloc((size_t)NN * KF * 2));  // pre-norm h (EPI1 out)
  float* ab = (float*)(ws + alloc((size_t)256 * 4));
  ushort* wt = (ushort*)(ws + alloc((size_t)(WT_L2 + NCLS * KF) * 2));
  ushort* t1b = featb;  // featb dead after reverse SpMM
  (void)ws_size;

  hipMemsetAsync(ws + z0, 0, (size_t)(TBUK + 512) * 4, stream);
  kb_hist<<<P1B, 256, 0, stream>>>(src, dst, gcount);
  kb_scan<<<1, 1024, 0, stream>>>(gcount, gbase, gcur);
  kb_place<<<P1B, 256, 0, stream>>>(src, dst, gcur, pairs_f, pairs_r);
  kb_build<<<TBUK, 256, 0, stream>>>(pairs_f, pairs_r, gbase, idx_f, idx_r,
                                     ptr_f, ptr_r, deg_in, deg_out);
  k_rsq<<<(NN + 255) / 256, 256, 0, stream>>>(deg_out, deg_in, ro, ri);
  k_convW<<<(WT_L2 + NCLS * KF + 255) / 256, 256, 0, stream>>>(Wb, Wh01, Wl01, W2, Wl2, wt);
  k_convF<<<NN * KF / 8 / 256, 256, 0, stream>>>(feat, ri, featb);

  const ushort* wtB[3] = {wt, wt + 16384, wt + 2 * 16384};
  const ushort* wtH[2] = {wt + 3 * 16384, wt + 4 * 16384};
  const ushort* wtL[2] = {wt + 5 * 16384, wt + 6 * 16384};
  const ushort* wtW2 = wt + WT_W2;
  const ushort* wtL2 = wt + WT_L2;

  int sb = (NN * 64 + 255) / 256;  // one wave per row
  // reverse conv SpMM once: aggb[u] = ro[u] * sum_{u->d} (feat*ri)[d]
  k_spmm_b<<<sb, 256, 0, stream>>>(featb, ptr_r, idx_r, ro, aggb);

  int mb = (NN + 63) / 64;
  // ---- layer 0 ----
  k_gemm<2, false, 0, false, false><<<mb, 256, 0, stream>>>(
      aggb, wtB[0], nullptr, nullptr, nullptr, feat, nullptr, ro, nullptr, hmaxb, hmaxs, nullptr);
  k_spmm_b<<<sb, 256, 0, stream>>>(hmaxs, ptr_f, idx_f, ri, t1b);
  k_gemm<2, true, 1, false, false><<<mb, 256, 0, stream>>>(
      t1b, wtH[0], hmaxb, wtL[0], nullptr, nullptr, nullptr, nullptr, nullptr, hpreb, nullptr, stat);
  k_stats_fin<<<1, 128, 0, stream>>>(stat, gamma, beta, ab);
  // ---- layer 1 ----  (norm of h folded into hprev read via ab)
  k_gemm<2, false, 0, false, true><<<mb, 256, 0, stream>>>(
      aggb, wtB[1], nullptr, nullptr, nullptr, hpreb, ab, ro, nullptr, hmaxb, hmaxs, nullptr);
  k_spmm_b<<<sb, 256, 0, stream>>>(hmaxs, ptr_f, idx_f, ri, t1b);
  k_gemm<2, true, 1, false, false><<<mb, 256, 0, stream>>>(
      t1b, wtH[1], hmaxb, wtL[1], nullptr, nullptr, nullptr, nullptr, nullptr, hpreb, nullptr, stat + 256);
  k_stats_fin<<<1, 128, 0, stream>>>(stat + 256, gamma + KF, beta + KF, ab);
  // ---- layer 2 ----
  k_gemm<2, false, 0, true, true><<<mb, 256, 0, stream>>>(
      aggb, wtB[2], nullptr, nullptr, bb2, hpreb, ab, ro, nullptr, hmaxb, hmaxs, nullptr);
  k_spmm_b<<<sb, 256, 0, stream>>>(hmaxs, ptr_f, idx_f, ri, t1b);
  k_gemm<2, true, 2, false, false><<<mb, 256, 0, stream>>>(
      t1b, wtW2, hmaxb, wtL2, b2, nullptr, nullptr, nullptr, out, nullptr, nullptr, nullptr);
}